// Round 1
// 2045.800 us; speedup vs baseline: 1.2884x; 1.2884x over previous
//
#include <hip/hip_runtime.h>

#define N_U 100000
#define N_B 20000
#define E_UB 3200000
#define E_UU 1600000
#define E_BB 320000
#define IN_DIM 384
#define D 128

// graph order: 0=bu (dst=ub_u), 1=uu (dst=uu_dst), 2=ub (dst=ub_b), 3=bb (dst=bb_dst)
#define B1 E_UB
#define B2 (E_UB + E_UU)
#define B3 (E_UB + E_UU + E_UB)
#define E_TOT (E_UB + E_UU + E_UB + E_BB)

// ---- coarse bins for the two-level LDS-presorted build ----
// rows per coarse bin = 1<<CSHg; bin bases come exactly from rowptr (no overflow for any input)
#define CSH0 9    // bu: 512 rows  -> NC0 = ceil(100000/512)  = 196  (~16.3K edges/bin)
#define CSH1 10   // uu: 1024 rows -> NC1 = ceil(100000/1024) = 98
#define CSH2 7    // ub: 128 rows  -> NC2 = 20000/128         = 157  (~20.4K edges/bin)
#define CSH3 10   // bb: 1024 rows -> NC3 = ceil(20000/1024)  = 20
#define NC0 196
#define NC1 98
#define NC2 157
#define NC3 20
#define CB1 NC0
#define CB2 (NC0 + NC1)
#define CB3 (NC0 + NC1 + NC2)
#define NC_TOT (NC0 + NC1 + NC2 + NC3)   // 471
#define NBIN 512                          // padded for LDS scan
#define BATCH 8192
#define NCHUNK ((E_TOT + BATCH - 1) / BATCH)

// ---------------- bf16 helpers ----------------

__device__ __forceinline__ unsigned bf16rn(float a) {
    unsigned ua = __float_as_uint(a);
    return (ua + 0x7fffu + ((ua >> 16) & 1u)) >> 16;
}

__device__ __forceinline__ void fma8(float* a, float w, uint4 u) {
    a[0] += w * __uint_as_float(u.x << 16);
    a[1] += w * __uint_as_float(u.x & 0xffff0000u);
    a[2] += w * __uint_as_float(u.y << 16);
    a[3] += w * __uint_as_float(u.y & 0xffff0000u);
    a[4] += w * __uint_as_float(u.z << 16);
    a[5] += w * __uint_as_float(u.z & 0xffff0000u);
    a[6] += w * __uint_as_float(u.w << 16);
    a[7] += w * __uint_as_float(u.w & 0xffff0000u);
}

// ---------------- CSR build ----------------

__global__ void count_all(const int* __restrict__ d0, const int* __restrict__ d1,
                          const int* __restrict__ d2, const int* __restrict__ d3,
                          int* __restrict__ cnt) {
    int stride = gridDim.x * blockDim.x;
    for (int gi = blockIdx.x * blockDim.x + threadIdx.x; gi < E_TOT; gi += stride) {
        if (gi < B1)       atomicAdd(&cnt[d0[gi]], 1);
        else if (gi < B2)  atomicAdd(&cnt[N_U + d1[gi - B1]], 1);
        else if (gi < B3)  atomicAdd(&cnt[2 * N_U + d2[gi - B2]], 1);
        else               atomicAdd(&cnt[2 * N_U + N_B + d3[gi - B3]], 1);
    }
}

// one block per graph; exclusive scan cnt -> rowptr
__global__ void scan4(int* c0, int* r0, int* c1, int* r1,
                      int* c2, int* r2, int* c3, int* r3) {
    __shared__ int sh[1024];
    int* cnt; int* rowptr; int n;
    switch (blockIdx.x) {
        case 0: cnt = c0; rowptr = r0; n = N_U; break;
        case 1: cnt = c1; rowptr = r1; n = N_U; break;
        case 2: cnt = c2; rowptr = r2; n = N_B; break;
        default: cnt = c3; rowptr = r3; n = N_B; break;
    }
    int t = threadIdx.x;
    int seg = (n + 1023) >> 10;
    int lo = t * seg;
    int hi = min(n, lo + seg);
    int s = 0;
    for (int i = lo; i < hi; ++i) s += cnt[i];
    sh[t] = s;
    __syncthreads();
    for (int off = 1; off < 1024; off <<= 1) {
        int add = 0;
        if (t >= off) add = sh[t - off];
        __syncthreads();
        sh[t] += add;
        __syncthreads();
    }
    int run = sh[t] - s;
    for (int i = lo; i < hi; ++i) {
        int c = cnt[i];
        rowptr[i] = run;
        run += c;
    }
    if (t == 1023) rowptr[n] = sh[1023];
}

// init per-coarse-bin append cursors from rowptr (absolute staging offsets incl. graph base)
__global__ void cbinit(const int* __restrict__ r0, const int* __restrict__ r1,
                       const int* __restrict__ r2, const int* __restrict__ r3,
                       int* __restrict__ gcur) {
    int i = blockIdx.x * blockDim.x + threadIdx.x;
    if (i >= NC_TOT) return;
    if (i < CB1)      gcur[i] = r0[i << CSH0];
    else if (i < CB2) gcur[i] = B1 + r1[(i - CB1) << CSH1];
    else if (i < CB3) gcur[i] = B2 + r2[(i - CB2) << CSH2];
    else              gcur[i] = B3 + r3[(i - CB3) << CSH3];
}

// binA: per-block chunk of 8192 edges -> LDS counting sort by coarse bin -> run-coalesced
// append into coarse-bin-contiguous staging. Record = {src | dloc<<17, val_bits}.
__global__ __launch_bounds__(256) void binA(
        const int* __restrict__ d0, const int* __restrict__ s0, const float* __restrict__ v0,
        const int* __restrict__ d1, const int* __restrict__ s1, const float* __restrict__ v1,
        const int* __restrict__ d2, const int* __restrict__ s2, const float* __restrict__ v2,
        const int* __restrict__ d3, const int* __restrict__ s3, const float* __restrict__ v3,
        int* __restrict__ gcur, int2* __restrict__ stage) {
    __shared__ int2 buf[BATCH];      // 64 KB
    __shared__ int hist[NBIN];
    __shared__ int scx[NBIN];        // exclusive scan (static, for the output search)
    __shared__ int cur[NBIN];        // running scatter cursors
    __shared__ int obase[NBIN];      // global base reserved for this block's run per bin
    int tid = threadIdx.x;
    int e0 = blockIdx.x * BATCH;
    int e1 = min(E_TOT, e0 + BATCH);

    for (int b = tid; b < NBIN; b += 256) hist[b] = 0;
    __syncthreads();

    // pass 1: histogram (dst only)
    for (int i = e0 + tid; i < e1; i += 256) {
        int bin;
        if (i < B1)      bin = d0[i] >> CSH0;
        else if (i < B2) bin = CB1 + (d1[i - B1] >> CSH1);
        else if (i < B3) bin = CB2 + (d2[i - B2] >> CSH2);
        else             bin = CB3 + (d3[i - B3] >> CSH3);
        atomicAdd(&hist[bin], 1);
    }
    __syncthreads();

    // inclusive LDS scan (Hillis-Steele, 256 threads x 2 elems)
    for (int b = tid; b < NBIN; b += 256) scx[b] = hist[b];
    __syncthreads();
    for (int off = 1; off < NBIN; off <<= 1) {
        int i0 = tid, i1 = tid + 256;
        int t0 = (i0 >= off) ? scx[i0 - off] : 0;
        int t1 = (i1 >= off) ? scx[i1 - off] : 0;
        __syncthreads();
        scx[i0] += t0;
        scx[i1] += t1;
        __syncthreads();
    }
    // exclusive bases, running cursors, one global reservation per nonempty bin
    for (int b = tid; b < NBIN; b += 256) {
        int h = hist[b];
        int ex = scx[b] - h;
        scx[b] = ex;
        cur[b] = ex;
        if (h > 0) obase[b] = atomicAdd(&gcur[b], h);
    }
    __syncthreads();

    // pass 2: re-read edges, scatter into LDS in bin order
    for (int i = e0 + tid; i < e1; i += 256) {
        int bin; int2 rec;
        if (i < B1) {
            int li = i;      int d = d0[li];
            rec.x = s0[li] | ((d & ((1 << CSH0) - 1)) << 17);
            rec.y = __float_as_int(v0[li]);
            bin = d >> CSH0;
        } else if (i < B2) {
            int li = i - B1; int d = d1[li];
            rec.x = s1[li] | ((d & ((1 << CSH1) - 1)) << 17);
            rec.y = __float_as_int(v1[li]);
            bin = CB1 + (d >> CSH1);
        } else if (i < B3) {
            int li = i - B2; int d = d2[li];
            rec.x = s2[li] | ((d & ((1 << CSH2) - 1)) << 17);
            rec.y = __float_as_int(v2[li]);
            bin = CB2 + (d >> CSH2);
        } else {
            int li = i - B3; int d = d3[li];
            rec.x = s3[li] | ((d & ((1 << CSH3) - 1)) << 17);
            rec.y = __float_as_int(v3[li]);
            bin = CB3 + (d >> CSH3);
        }
        int p = atomicAdd(&cur[bin], 1);
        buf[p] = rec;
    }
    __syncthreads();

    // write out: slot j belongs to bin = max b with scx[b] <= j; runs are contiguous in global
    int cntE = e1 - e0;
    for (int j = tid; j < cntE; j += 256) {
        int lo = 0, hi = NBIN - 1;
        while (lo < hi) {
            int mid = (lo + hi + 1) >> 1;
            if (scx[mid] <= j) lo = mid; else hi = mid - 1;
        }
        stage[obase[lo] + (j - scx[lo])] = buf[j];
    }
}

// binB: one block per coarse bin; per-row counting sort into final CSR.
// Scatter window = bin's CSR range (~130-160 KB) written by ONE block (one XCD) -> lines
// fill fully in its L2; staging reads are contiguous.
__global__ __launch_bounds__(512) void binB(
        const int* __restrict__ r0, const int* __restrict__ r1,
        const int* __restrict__ r2, const int* __restrict__ r3,
        int2* __restrict__ e0, int2* __restrict__ e1,
        int2* __restrict__ e2, int2* __restrict__ e3,
        const int2* __restrict__ stage) {
    __shared__ int lcur[1024];
    int b = blockIdx.x;
    const int* rp; int2* eo; int n, k, csh, ebase;
    if (b < CB1)       { k = b;       rp = r0; eo = e0; n = N_U; csh = CSH0; ebase = 0;  }
    else if (b < CB2)  { k = b - CB1; rp = r1; eo = e1; n = N_U; csh = CSH1; ebase = B1; }
    else if (b < CB3)  { k = b - CB2; rp = r2; eo = e2; n = N_B; csh = CSH2; ebase = B2; }
    else               { k = b - CB3; rp = r3; eo = e3; n = N_B; csh = CSH3; ebase = B3; }
    int lo = k << csh;
    int hi = min(n, lo + (1 << csh));
    int rows = hi - lo;
    for (int j = threadIdx.x; j < rows; j += 512) lcur[j] = rp[lo + j];
    __syncthreads();
    int base = rp[lo];
    int cnt = rp[hi] - base;
    for (int i = threadIdx.x; i < cnt; i += 512) {
        int2 rec = stage[ebase + base + i];
        int p = atomicAdd(&lcur[((unsigned)rec.x) >> 17], 1);
        eo[p] = make_int2(rec.x & 0x1FFFF, rec.y);
    }
}

// ---------------- dense GEMM: cur(bf16) and sum(fp32) = X[n,384] @ W[384,128] ----------------

__global__ void gemm_kernel(const float* __restrict__ X, const float* __restrict__ W, int n,
                            unsigned* __restrict__ curh, float* __restrict__ sum) {
    __shared__ float sx[8 * IN_DIM];
    int base = blockIdx.x * 8;
    for (int i = threadIdx.x; i < 8 * IN_DIM; i += 256) {
        int r = base + i / IN_DIM;
        sx[i] = (r < n) ? X[(size_t)r * IN_DIM + (i % IN_DIM)] : 0.f;
    }
    __syncthreads();
    int col = threadIdx.x & 127;
    int rh  = threadIdx.x >> 7;  // 0 or 1
    float acc[4] = {0.f, 0.f, 0.f, 0.f};
    for (int k = 0; k < IN_DIM; ++k) {
        float wv = W[k * D + col];
#pragma unroll
        for (int j = 0; j < 4; ++j)
            acc[j] += sx[(rh * 4 + j) * IN_DIM + k] * wv;
    }
#pragma unroll
    for (int j = 0; j < 4; ++j) {
        int r = base + rh * 4 + j;
        if (r < n) {
            size_t o = (size_t)r * D + col;
            sum[o] = acc[j];
            ((unsigned short*)curh)[o] = (unsigned short)bf16rn(acc[j]);
        }
    }
}

// ---------------- fused pull SpMM ----------------
// One wave per dst row, 4 quarters x 16 lanes; each quarter owns one edge; lane gathers
// uint4 (16B) of the 256B bf16 source row; unroll x2 -> 2KB of gathers in flight.

__global__ void spmm_fused(const int* __restrict__ rp1, const int2* __restrict__ e1,
                           const int* __restrict__ rp2, const int2* __restrict__ e2,
                           const uint4* __restrict__ x1, const uint4* __restrict__ x2,
                           uint4* __restrict__ y_nxt, float4* __restrict__ sum, int n) {
    int wave = threadIdx.x >> 6;
    int lane = threadIdx.x & 63;
    int q = lane >> 4;
    int l = lane & 15;
    int r = blockIdx.x * 4 + wave;
    if (r >= n) return;

    float acc[8];
#pragma unroll
    for (int k = 0; k < 8; ++k) acc[k] = 0.f;

#pragma unroll
    for (int pass = 0; pass < 2; ++pass) {
        const int* rp = pass ? rp2 : rp1;
        const int2* edges = pass ? e2 : e1;
        const uint4* xv = pass ? x2 : x1;
        int s = rp[r], e = rp[r + 1];
        int i = s;
        for (; i + 8 <= e; i += 8) {
            int2 edA = edges[i + q];
            int2 edB = edges[i + 4 + q];
            uint4 uA = xv[(size_t)edA.x * 16 + l];
            uint4 uB = xv[(size_t)edB.x * 16 + l];
            fma8(acc, __int_as_float(edA.y), uA);
            fma8(acc, __int_as_float(edB.y), uB);
        }
        if (i < e) {
            int idx = i + q;
            bool valid = idx < e;
            int2 ed = edges[valid ? idx : (e - 1)];
            uint4 u = xv[(size_t)ed.x * 16 + l];
            fma8(acc, valid ? __int_as_float(ed.y) : 0.f, u);
            i += 4;
            if (i < e) {
                idx = i + q;
                valid = idx < e;
                int2 ed2 = edges[valid ? idx : (e - 1)];
                uint4 u2 = xv[(size_t)ed2.x * 16 + l];
                fma8(acc, valid ? __int_as_float(ed2.y) : 0.f, u2);
            }
        }
    }

#pragma unroll
    for (int k = 0; k < 8; ++k) {
        acc[k] += __shfl_xor(acc[k], 16);
        acc[k] += __shfl_xor(acc[k], 32);
    }

    if (q == 0) {
        uint4 p;
        p.x = bf16rn(acc[0]) | (bf16rn(acc[1]) << 16);
        p.y = bf16rn(acc[2]) | (bf16rn(acc[3]) << 16);
        p.z = bf16rn(acc[4]) | (bf16rn(acc[5]) << 16);
        p.w = bf16rn(acc[6]) | (bf16rn(acc[7]) << 16);
        y_nxt[(size_t)r * 16 + l] = p;
        float4* sp = sum + (size_t)r * 32 + 2 * l;
        float4 s0 = sp[0], s1 = sp[1];
        s0.x += acc[0]; s0.y += acc[1]; s0.z += acc[2]; s0.w += acc[3];
        s1.x += acc[4]; s1.y += acc[5]; s1.z += acc[6]; s1.w += acc[7];
        sp[0] = s0; sp[1] = s1;
    }
}

// ---------------- normalize ----------------

__global__ void norm_kernel(float* __restrict__ out, int n) {
    int wave = threadIdx.x >> 6;
    int lane = threadIdx.x & 63;
    int r = blockIdx.x * 4 + wave;
    if (r >= n) return;
    float2* p = (float2*)out + (size_t)r * 64 + lane;
    float2 v = *p;
    v.x *= 0.25f;
    v.y *= 0.25f;
    float ss = v.x * v.x + v.y * v.y;
    for (int off = 32; off > 0; off >>= 1) ss += __shfl_down(ss, off);
    ss = __shfl(ss, 0);
    float inv = 1.f / fmaxf(sqrtf(ss), 1e-12f);
    v.x *= inv;
    v.y *= inv;
    *p = v;
}

// ---------------- launch ----------------

extern "C" void kernel_launch(void* const* d_in, const int* in_sizes, int n_in,
                              void* d_out, int out_size, void* d_ws, size_t ws_size,
                              hipStream_t stream) {
    const float* user_feat = (const float*)d_in[0];
    const float* biz_feat  = (const float*)d_in[1];
    const float* W_user    = (const float*)d_in[2];
    const float* W_biz     = (const float*)d_in[3];
    const int*   ub_u      = (const int*)d_in[4];
    const int*   ub_b      = (const int*)d_in[5];
    const float* val_ub    = (const float*)d_in[6];
    const float* val_bu    = (const float*)d_in[7];
    const int*   uu_src    = (const int*)d_in[8];
    const int*   uu_dst    = (const int*)d_in[9];
    const float* uu_val    = (const float*)d_in[10];
    const int*   bb_src    = (const int*)d_in[11];
    const int*   bb_dst    = (const int*)d_in[12];
    const float* bb_val    = (const float*)d_in[13];

    float* out   = (float*)d_out;
    float* u_sum = out;
    float* b_sum = out + (size_t)N_U * D;

    char* ws = (char*)d_ws;
    size_t off = 0;
    auto alloc = [&](size_t bytes) -> void* {
        void* p = ws + off;
        off += (bytes + 255) & ~(size_t)255;
        return p;
    };
    unsigned* u_curh = (unsigned*)alloc((size_t)N_U * 64 * 4);   // bf16 [N_U,128]
    unsigned* b_curh = (unsigned*)alloc((size_t)N_B * 64 * 4);
    int2* e_bu = (int2*)alloc((size_t)E_UB * 8);
    int2* e_uu = (int2*)alloc((size_t)E_UU * 8);
    int2* e_ub = (int2*)alloc((size_t)E_UB * 8);
    int2* e_bb = (int2*)alloc((size_t)E_BB * 8);
    int*  cnt  = (int*)alloc((size_t)(2 * N_U + 2 * N_B) * 4);
    int*  rp_bu = (int*)alloc((N_U + 1) * 4);
    int*  rp_uu = (int*)alloc((N_U + 1) * 4);
    int*  rp_ub = (int*)alloc((N_B + 1) * 4);
    int*  rp_bb = (int*)alloc((N_B + 1) * 4);
    int*  gcur  = (int*)alloc(NC_TOT * 4);
    // staging region; u_nxth/b_nxth alias its head (used only after binB completes)
    int2* stage = (int2*)alloc((size_t)E_TOT * 8);
    unsigned* u_nxth = (unsigned*)stage;
    unsigned* b_nxth = (unsigned*)((char*)stage + (size_t)N_U * 64 * 4);

    int* cnt_bu = cnt;
    int* cnt_uu = cnt + N_U;
    int* cnt_ub = cnt + 2 * N_U;
    int* cnt_bb = cnt + 2 * N_U + N_B;

    hipMemsetAsync(cnt, 0, sizeof(int) * (2 * N_U + 2 * N_B), stream);

    count_all<<<4096, 256, 0, stream>>>(ub_u, uu_dst, ub_b, bb_dst, cnt);
    scan4<<<4, 1024, 0, stream>>>(cnt_bu, rp_bu, cnt_uu, rp_uu, cnt_ub, rp_ub, cnt_bb, rp_bb);
    cbinit<<<(NC_TOT + 255) / 256, 256, 0, stream>>>(rp_bu, rp_uu, rp_ub, rp_bb, gcur);
    binA<<<NCHUNK, 256, 0, stream>>>(ub_u,   ub_b,   val_bu,
                                     uu_dst, uu_src, uu_val,
                                     ub_b,   ub_u,   val_ub,
                                     bb_dst, bb_src, bb_val,
                                     gcur, stage);
    binB<<<NC_TOT, 512, 0, stream>>>(rp_bu, rp_uu, rp_ub, rp_bb,
                                     e_bu, e_uu, e_ub, e_bb, stage);

    gemm_kernel<<<(N_U + 7) / 8, 256, 0, stream>>>(user_feat, W_user, N_U, u_curh, u_sum);
    gemm_kernel<<<(N_B + 7) / 8, 256, 0, stream>>>(biz_feat,  W_biz,  N_B, b_curh, b_sum);

    for (int l = 0; l < 3; ++l) {
        spmm_fused<<<(N_U + 3) / 4, 256, 0, stream>>>(rp_bu, e_bu, rp_uu, e_uu,
                                                      (const uint4*)b_curh, (const uint4*)u_curh,
                                                      (uint4*)u_nxth, (float4*)u_sum, N_U);
        spmm_fused<<<(N_B + 3) / 4, 256, 0, stream>>>(rp_ub, e_ub, rp_bb, e_bb,
                                                      (const uint4*)u_curh, (const uint4*)b_curh,
                                                      (uint4*)b_nxth, (float4*)b_sum, N_B);
        unsigned* t;
        t = u_curh; u_curh = u_nxth; u_nxth = t;
        t = b_curh; b_curh = b_nxth; b_nxth = t;
    }

    norm_kernel<<<(N_U + 3) / 4, 256, 0, stream>>>(u_sum, N_U);
    norm_kernel<<<(N_B + 3) / 4, 256, 0, stream>>>(b_sum, N_B);
}

// Round 2
// 1608.450 us; speedup vs baseline: 1.6388x; 1.2719x over previous
//
#include <hip/hip_runtime.h>

#define N_U 100000
#define N_B 20000
#define E_UB 3200000
#define E_UU 1600000
#define E_BB 320000
#define IN_DIM 384
#define D 128

// graph order: 0=bu (dst=ub_u), 1=uu (dst=uu_dst), 2=ub (dst=ub_b), 3=bb (dst=bb_dst)
#define B1 E_UB
#define B2 (E_UB + E_UU)
#define B3 (E_UB + E_UU + E_UB)
#define E_TOT (E_UB + E_UU + E_UB + E_BB)

// ---- coarse bins for the two-level LDS-presorted build ----
// rows per coarse bin = 1<<CSHg; bin bases come exactly from coarse counts (no overflow
// possible for any input: capacity == exact count)
#define CSH0 9    // bu: 512 rows  -> NC0 = ceil(100000/512)  = 196  (~16.3K edges/bin)
#define CSH1 10   // uu: 1024 rows -> NC1 = ceil(100000/1024) = 98
#define CSH2 7    // ub: 128 rows  -> NC2 = 20000/128         = 157  (~20.4K edges/bin)
#define CSH3 10   // bb: 1024 rows -> NC3 = ceil(20000/1024)  = 20
#define NC0 196
#define NC1 98
#define NC2 157
#define NC3 20
#define CB1 NC0
#define CB2 (NC0 + NC1)
#define CB3 (NC0 + NC1 + NC2)
#define NC_TOT (NC0 + NC1 + NC2 + NC3)   // 471
#define NBIN 512                          // padded for LDS scan
#define BATCH 8192
#define NCHUNK ((E_TOT + BATCH - 1) / BATCH)

// ---------------- bf16 helpers ----------------

__device__ __forceinline__ unsigned bf16rn(float a) {
    unsigned ua = __float_as_uint(a);
    return (ua + 0x7fffu + ((ua >> 16) & 1u)) >> 16;
}

__device__ __forceinline__ void fma8(float* a, float w, uint4 u) {
    a[0] += w * __uint_as_float(u.x << 16);
    a[1] += w * __uint_as_float(u.x & 0xffff0000u);
    a[2] += w * __uint_as_float(u.y << 16);
    a[3] += w * __uint_as_float(u.y & 0xffff0000u);
    a[4] += w * __uint_as_float(u.z << 16);
    a[5] += w * __uint_as_float(u.z & 0xffff0000u);
    a[6] += w * __uint_as_float(u.w << 16);
    a[7] += w * __uint_as_float(u.w & 0xffff0000u);
}

// ---------------- CSR build ----------------

// coarse histogram (471 bins) via per-block LDS hist; replaces per-row count_all
// (8.32M device-scope atomics -> ~480K, no 258MB memory-side RMW traffic)
__global__ __launch_bounds__(256) void coarse_count(
        const int* __restrict__ d0, const int* __restrict__ d1,
        const int* __restrict__ d2, const int* __restrict__ d3,
        int* __restrict__ ccnt) {
    __shared__ int h[NBIN];
    for (int b = threadIdx.x; b < NBIN; b += 256) h[b] = 0;
    __syncthreads();
    int stride = gridDim.x * blockDim.x;
    for (int gi = blockIdx.x * blockDim.x + threadIdx.x; gi < E_TOT; gi += stride) {
        int bin;
        if (gi < B1)      bin = d0[gi] >> CSH0;
        else if (gi < B2) bin = CB1 + (d1[gi - B1] >> CSH1);
        else if (gi < B3) bin = CB2 + (d2[gi - B2] >> CSH2);
        else              bin = CB3 + (d3[gi - B3] >> CSH3);
        atomicAdd(&h[bin], 1);
    }
    __syncthreads();
    for (int b = threadIdx.x; b < NC_TOT; b += 256) {
        int v = h[b];
        if (v) atomicAdd(&ccnt[b], v);
    }
}

// single block: segmented exclusive scan of coarse counts ->
// gb[i]   = within-graph edge offset of bin i (CSR base of its first row)
// gcur[i] = absolute staging append cursor (graph base + gb)
__global__ __launch_bounds__(512) void cscan(const int* __restrict__ ccnt,
                                             int* __restrict__ gb,
                                             int* __restrict__ gcur) {
    __shared__ int sh[512];
    int t = threadIdx.x;
    int c = (t < NC_TOT) ? ccnt[t] : 0;
    sh[t] = c;
    __syncthreads();
    for (int off = 1; off < 512; off <<= 1) {
        int v = (t >= off) ? sh[t - off] : 0;
        __syncthreads();
        sh[t] += v;
        __syncthreads();
    }
    if (t < NC_TOT) {
        int excl = sh[t] - c;
        int pre, gbase;
        if (t < CB1)      { pre = 0;           gbase = 0;  }
        else if (t < CB2) { pre = sh[CB1 - 1]; gbase = B1; }
        else if (t < CB3) { pre = sh[CB2 - 1]; gbase = B2; }
        else              { pre = sh[CB3 - 1]; gbase = B3; }
        int wb = excl - pre;
        gb[t] = wb;
        gcur[t] = gbase + wb;
    }
}

// binA: per-block chunk of 8192 edges -> LDS counting sort by coarse bin -> run-coalesced
// append into coarse-bin-contiguous staging. Record = {src | dloc<<17, val_bits}.
__global__ __launch_bounds__(256) void binA(
        const int* __restrict__ d0, const int* __restrict__ s0, const float* __restrict__ v0,
        const int* __restrict__ d1, const int* __restrict__ s1, const float* __restrict__ v1,
        const int* __restrict__ d2, const int* __restrict__ s2, const float* __restrict__ v2,
        const int* __restrict__ d3, const int* __restrict__ s3, const float* __restrict__ v3,
        int* __restrict__ gcur, int2* __restrict__ stage) {
    __shared__ int2 buf[BATCH];      // 64 KB
    __shared__ int hist[NBIN];
    __shared__ int scx[NBIN];        // exclusive scan (static, for the output search)
    __shared__ int cur[NBIN];        // running scatter cursors
    __shared__ int obase[NBIN];      // global base reserved for this block's run per bin
    int tid = threadIdx.x;
    int e0 = blockIdx.x * BATCH;
    int e1 = min(E_TOT, e0 + BATCH);

    for (int b = tid; b < NBIN; b += 256) hist[b] = 0;
    __syncthreads();

    // pass 1: histogram (dst only)
    for (int i = e0 + tid; i < e1; i += 256) {
        int bin;
        if (i < B1)      bin = d0[i] >> CSH0;
        else if (i < B2) bin = CB1 + (d1[i - B1] >> CSH1);
        else if (i < B3) bin = CB2 + (d2[i - B2] >> CSH2);
        else             bin = CB3 + (d3[i - B3] >> CSH3);
        atomicAdd(&hist[bin], 1);
    }
    __syncthreads();

    // inclusive LDS scan (Hillis-Steele, 256 threads x 2 elems)
    for (int b = tid; b < NBIN; b += 256) scx[b] = hist[b];
    __syncthreads();
    for (int off = 1; off < NBIN; off <<= 1) {
        int i0 = tid, i1 = tid + 256;
        int t0 = (i0 >= off) ? scx[i0 - off] : 0;
        int t1 = (i1 >= off) ? scx[i1 - off] : 0;
        __syncthreads();
        scx[i0] += t0;
        scx[i1] += t1;
        __syncthreads();
    }
    // exclusive bases, running cursors, one global reservation per nonempty bin
    for (int b = tid; b < NBIN; b += 256) {
        int h = hist[b];
        int ex = scx[b] - h;
        scx[b] = ex;
        cur[b] = ex;
        if (h > 0) obase[b] = atomicAdd(&gcur[b], h);
    }
    __syncthreads();

    // pass 2: re-read edges, scatter into LDS in bin order
    for (int i = e0 + tid; i < e1; i += 256) {
        int bin; int2 rec;
        if (i < B1) {
            int li = i;      int d = d0[li];
            rec.x = s0[li] | ((d & ((1 << CSH0) - 1)) << 17);
            rec.y = __float_as_int(v0[li]);
            bin = d >> CSH0;
        } else if (i < B2) {
            int li = i - B1; int d = d1[li];
            rec.x = s1[li] | ((d & ((1 << CSH1) - 1)) << 17);
            rec.y = __float_as_int(v1[li]);
            bin = CB1 + (d >> CSH1);
        } else if (i < B3) {
            int li = i - B2; int d = d2[li];
            rec.x = s2[li] | ((d & ((1 << CSH2) - 1)) << 17);
            rec.y = __float_as_int(v2[li]);
            bin = CB2 + (d >> CSH2);
        } else {
            int li = i - B3; int d = d3[li];
            rec.x = s3[li] | ((d & ((1 << CSH3) - 1)) << 17);
            rec.y = __float_as_int(v3[li]);
            bin = CB3 + (d >> CSH3);
        }
        int p = atomicAdd(&cur[bin], 1);
        buf[p] = rec;
    }
    __syncthreads();

    // write out: slot j belongs to bin = max b with scx[b] <= j; runs are contiguous in global
    int cntE = e1 - e0;
    for (int j = tid; j < cntE; j += 256) {
        int lo = 0, hi = NBIN - 1;
        while (lo < hi) {
            int mid = (lo + hi + 1) >> 1;
            if (scx[mid] <= j) lo = mid; else hi = mid - 1;
        }
        stage[obase[lo] + (j - scx[lo])] = buf[j];
    }
}

// binB: one block per coarse bin; counts its own per-row histogram in LDS, scans it,
// writes the rowptr segment, then per-row counting sort into final CSR.
// Staging region per bin (~150 KB) is L2-hot after the count pass; scatter window is
// written by ONE block (one XCD) -> lines fill fully in its L2.
__global__ __launch_bounds__(512) void binB(
        int* __restrict__ r0, int* __restrict__ r1,
        int* __restrict__ r2, int* __restrict__ r3,
        int2* __restrict__ e0, int2* __restrict__ e1,
        int2* __restrict__ e2, int2* __restrict__ e3,
        const int* __restrict__ gb, const int2* __restrict__ stage) {
    __shared__ int lc[1024];
    __shared__ int lcur[1024];
    int b = blockIdx.x;
    int* rp; int2* eo; int n, k, csh, ebase, Eg, nbEnd;
    if (b < CB1)       { k = b;       rp = r0; eo = e0; n = N_U; csh = CSH0; ebase = 0;  Eg = E_UB; nbEnd = CB1;    }
    else if (b < CB2)  { k = b - CB1; rp = r1; eo = e1; n = N_U; csh = CSH1; ebase = B1; Eg = E_UU; nbEnd = CB2;    }
    else if (b < CB3)  { k = b - CB2; rp = r2; eo = e2; n = N_B; csh = CSH2; ebase = B2; Eg = E_UB; nbEnd = CB3;    }
    else               { k = b - CB3; rp = r3; eo = e3; n = N_B; csh = CSH3; ebase = B3; Eg = E_BB; nbEnd = NC_TOT; }
    int lo = k << csh;
    int hi = min(n, lo + (1 << csh));
    int rows = hi - lo;
    int base = gb[b];
    int cnt = ((b + 1 < nbEnd) ? gb[b + 1] : Eg) - base;
    const int2* sp = stage + ebase + base;

    for (int j = threadIdx.x; j < 1024; j += 512) lc[j] = 0;
    __syncthreads();
    // pass 1: per-row counts
    for (int i = threadIdx.x; i < cnt; i += 512)
        atomicAdd(&lc[((unsigned)sp[i].x) >> 17], 1);
    __syncthreads();
    // inclusive scan of lc[1024] (Hillis-Steele, 512 threads x 2 elems)
    for (int off = 1; off < 1024; off <<= 1) {
        int i0 = threadIdx.x, i1 = threadIdx.x + 512;
        int t0 = (i0 >= off) ? lc[i0 - off] : 0;
        int t1 = (i1 >= off) ? lc[i1 - off] : 0;
        __syncthreads();
        lc[i0] += t0;
        lc[i1] += t1;
        __syncthreads();
    }
    // rowptr segment + scatter cursors (exclusive scan = inclusive[j-1])
    for (int j = threadIdx.x; j < rows; j += 512) {
        int ex = base + ((j > 0) ? lc[j - 1] : 0);
        rp[lo + j] = ex;
        lcur[j] = ex;
    }
    if (threadIdx.x == 0 && hi == n) rp[n] = Eg;
    __syncthreads();
    // pass 2: scatter (staging L2-resident from pass 1)
    for (int i = threadIdx.x; i < cnt; i += 512) {
        int2 rec = sp[i];
        int p = atomicAdd(&lcur[((unsigned)rec.x) >> 17], 1);
        eo[p] = make_int2(rec.x & 0x1FFFF, rec.y);
    }
}

// ---------------- dense GEMM: cur(bf16) and sum(fp32) = X[n,384] @ W[384,128] ----------------

__global__ void gemm_kernel(const float* __restrict__ X, const float* __restrict__ W, int n,
                            unsigned* __restrict__ curh, float* __restrict__ sum) {
    __shared__ float sx[8 * IN_DIM];
    int base = blockIdx.x * 8;
    for (int i = threadIdx.x; i < 8 * IN_DIM; i += 256) {
        int r = base + i / IN_DIM;
        sx[i] = (r < n) ? X[(size_t)r * IN_DIM + (i % IN_DIM)] : 0.f;
    }
    __syncthreads();
    int col = threadIdx.x & 127;
    int rh  = threadIdx.x >> 7;  // 0 or 1
    float acc[4] = {0.f, 0.f, 0.f, 0.f};
    for (int k = 0; k < IN_DIM; ++k) {
        float wv = W[k * D + col];
#pragma unroll
        for (int j = 0; j < 4; ++j)
            acc[j] += sx[(rh * 4 + j) * IN_DIM + k] * wv;
    }
#pragma unroll
    for (int j = 0; j < 4; ++j) {
        int r = base + rh * 4 + j;
        if (r < n) {
            size_t o = (size_t)r * D + col;
            sum[o] = acc[j];
            ((unsigned short*)curh)[o] = (unsigned short)bf16rn(acc[j]);
        }
    }
}

// ---------------- fused pull SpMM ----------------
// One wave per dst row, 4 quarters x 16 lanes; each quarter owns one edge; lane gathers
// uint4 (16B) of the 256B bf16 source row; unroll x2 -> 2KB of gathers in flight.

__global__ void spmm_fused(const int* __restrict__ rp1, const int2* __restrict__ e1,
                           const int* __restrict__ rp2, const int2* __restrict__ e2,
                           const uint4* __restrict__ x1, const uint4* __restrict__ x2,
                           uint4* __restrict__ y_nxt, float4* __restrict__ sum, int n) {
    int wave = threadIdx.x >> 6;
    int lane = threadIdx.x & 63;
    int q = lane >> 4;
    int l = lane & 15;
    int r = blockIdx.x * 4 + wave;
    if (r >= n) return;

    float acc[8];
#pragma unroll
    for (int k = 0; k < 8; ++k) acc[k] = 0.f;

#pragma unroll
    for (int pass = 0; pass < 2; ++pass) {
        const int* rp = pass ? rp2 : rp1;
        const int2* edges = pass ? e2 : e1;
        const uint4* xv = pass ? x2 : x1;
        int s = rp[r], e = rp[r + 1];
        int i = s;
        for (; i + 8 <= e; i += 8) {
            int2 edA = edges[i + q];
            int2 edB = edges[i + 4 + q];
            uint4 uA = xv[(size_t)edA.x * 16 + l];
            uint4 uB = xv[(size_t)edB.x * 16 + l];
            fma8(acc, __int_as_float(edA.y), uA);
            fma8(acc, __int_as_float(edB.y), uB);
        }
        if (i < e) {
            int idx = i + q;
            bool valid = idx < e;
            int2 ed = edges[valid ? idx : (e - 1)];
            uint4 u = xv[(size_t)ed.x * 16 + l];
            fma8(acc, valid ? __int_as_float(ed.y) : 0.f, u);
            i += 4;
            if (i < e) {
                idx = i + q;
                valid = idx < e;
                int2 ed2 = edges[valid ? idx : (e - 1)];
                uint4 u2 = xv[(size_t)ed2.x * 16 + l];
                fma8(acc, valid ? __int_as_float(ed2.y) : 0.f, u2);
            }
        }
    }

#pragma unroll
    for (int k = 0; k < 8; ++k) {
        acc[k] += __shfl_xor(acc[k], 16);
        acc[k] += __shfl_xor(acc[k], 32);
    }

    if (q == 0) {
        uint4 p;
        p.x = bf16rn(acc[0]) | (bf16rn(acc[1]) << 16);
        p.y = bf16rn(acc[2]) | (bf16rn(acc[3]) << 16);
        p.z = bf16rn(acc[4]) | (bf16rn(acc[5]) << 16);
        p.w = bf16rn(acc[6]) | (bf16rn(acc[7]) << 16);
        y_nxt[(size_t)r * 16 + l] = p;
        float4* sp = sum + (size_t)r * 32 + 2 * l;
        float4 s0 = sp[0], s1 = sp[1];
        s0.x += acc[0]; s0.y += acc[1]; s0.z += acc[2]; s0.w += acc[3];
        s1.x += acc[4]; s1.y += acc[5]; s1.z += acc[6]; s1.w += acc[7];
        sp[0] = s0; sp[1] = s1;
    }
}

// ---------------- normalize ----------------

__global__ void norm_kernel(float* __restrict__ out, int n) {
    int wave = threadIdx.x >> 6;
    int lane = threadIdx.x & 63;
    int r = blockIdx.x * 4 + wave;
    if (r >= n) return;
    float2* p = (float2*)out + (size_t)r * 64 + lane;
    float2 v = *p;
    v.x *= 0.25f;
    v.y *= 0.25f;
    float ss = v.x * v.x + v.y * v.y;
    for (int off = 32; off > 0; off >>= 1) ss += __shfl_down(ss, off);
    ss = __shfl(ss, 0);
    float inv = 1.f / fmaxf(sqrtf(ss), 1e-12f);
    v.x *= inv;
    v.y *= inv;
    *p = v;
}

// ---------------- launch ----------------

extern "C" void kernel_launch(void* const* d_in, const int* in_sizes, int n_in,
                              void* d_out, int out_size, void* d_ws, size_t ws_size,
                              hipStream_t stream) {
    const float* user_feat = (const float*)d_in[0];
    const float* biz_feat  = (const float*)d_in[1];
    const float* W_user    = (const float*)d_in[2];
    const float* W_biz     = (const float*)d_in[3];
    const int*   ub_u      = (const int*)d_in[4];
    const int*   ub_b      = (const int*)d_in[5];
    const float* val_ub    = (const float*)d_in[6];
    const float* val_bu    = (const float*)d_in[7];
    const int*   uu_src    = (const int*)d_in[8];
    const int*   uu_dst    = (const int*)d_in[9];
    const float* uu_val    = (const float*)d_in[10];
    const int*   bb_src    = (const int*)d_in[11];
    const int*   bb_dst    = (const int*)d_in[12];
    const float* bb_val    = (const float*)d_in[13];

    float* out   = (float*)d_out;
    float* u_sum = out;
    float* b_sum = out + (size_t)N_U * D;

    char* ws = (char*)d_ws;
    size_t off = 0;
    auto alloc = [&](size_t bytes) -> void* {
        void* p = ws + off;
        off += (bytes + 255) & ~(size_t)255;
        return p;
    };
    unsigned* u_curh = (unsigned*)alloc((size_t)N_U * 64 * 4);   // bf16 [N_U,128]
    unsigned* b_curh = (unsigned*)alloc((size_t)N_B * 64 * 4);
    int2* e_bu = (int2*)alloc((size_t)E_UB * 8);
    int2* e_uu = (int2*)alloc((size_t)E_UU * 8);
    int2* e_ub = (int2*)alloc((size_t)E_UB * 8);
    int2* e_bb = (int2*)alloc((size_t)E_BB * 8);
    int*  ccnt = (int*)alloc(NC_TOT * 4);
    int*  gb   = (int*)alloc(NC_TOT * 4);
    int*  gcur = (int*)alloc(NC_TOT * 4);
    int*  rp_bu = (int*)alloc((N_U + 1) * 4);
    int*  rp_uu = (int*)alloc((N_U + 1) * 4);
    int*  rp_ub = (int*)alloc((N_B + 1) * 4);
    int*  rp_bb = (int*)alloc((N_B + 1) * 4);
    // staging region; u_nxth/b_nxth alias its head (used only after binB completes)
    int2* stage = (int2*)alloc((size_t)E_TOT * 8);
    unsigned* u_nxth = (unsigned*)stage;
    unsigned* b_nxth = (unsigned*)((char*)stage + (size_t)N_U * 64 * 4);

    hipMemsetAsync(ccnt, 0, sizeof(int) * NC_TOT, stream);

    coarse_count<<<1024, 256, 0, stream>>>(ub_u, uu_dst, ub_b, bb_dst, ccnt);
    cscan<<<1, 512, 0, stream>>>(ccnt, gb, gcur);
    binA<<<NCHUNK, 256, 0, stream>>>(ub_u,   ub_b,   val_bu,
                                     uu_dst, uu_src, uu_val,
                                     ub_b,   ub_u,   val_ub,
                                     bb_dst, bb_src, bb_val,
                                     gcur, stage);
    binB<<<NC_TOT, 512, 0, stream>>>(rp_bu, rp_uu, rp_ub, rp_bb,
                                     e_bu, e_uu, e_ub, e_bb, gb, stage);

    gemm_kernel<<<(N_U + 7) / 8, 256, 0, stream>>>(user_feat, W_user, N_U, u_curh, u_sum);
    gemm_kernel<<<(N_B + 7) / 8, 256, 0, stream>>>(biz_feat,  W_biz,  N_B, b_curh, b_sum);

    for (int l = 0; l < 3; ++l) {
        spmm_fused<<<(N_U + 3) / 4, 256, 0, stream>>>(rp_bu, e_bu, rp_uu, e_uu,
                                                      (const uint4*)b_curh, (const uint4*)u_curh,
                                                      (uint4*)u_nxth, (float4*)u_sum, N_U);
        spmm_fused<<<(N_B + 3) / 4, 256, 0, stream>>>(rp_ub, e_ub, rp_bb, e_bb,
                                                      (const uint4*)u_curh, (const uint4*)b_curh,
                                                      (uint4*)b_nxth, (float4*)b_sum, N_B);
        unsigned* t;
        t = u_curh; u_curh = u_nxth; u_nxth = t;
        t = b_curh; b_curh = b_nxth; b_nxth = t;
    }

    norm_kernel<<<(N_U + 3) / 4, 256, 0, stream>>>(u_sum, N_U);
    norm_kernel<<<(N_B + 3) / 4, 256, 0, stream>>>(b_sum, N_B);
}

// Round 3
// 1528.596 us; speedup vs baseline: 1.7244x; 1.0522x over previous
//
#include <hip/hip_runtime.h>

#define N_U 100000
#define N_B 20000
#define E_UB 3200000
#define E_UU 1600000
#define E_BB 320000
#define IN_DIM 384
#define D 128

// graph order: 0=bu (dst=ub_u), 1=uu (dst=uu_dst), 2=ub (dst=ub_b), 3=bb (dst=bb_dst)
#define B1 E_UB
#define B2 (E_UB + E_UU)
#define B3 (E_UB + E_UU + E_UB)
#define E_TOT (E_UB + E_UU + E_UB + E_BB)

// ---- coarse bins for the two-level LDS-presorted build ----
#define CSH0 9
#define CSH1 10
#define CSH2 7
#define CSH3 10
#define NC0 196
#define NC1 98
#define NC2 157
#define NC3 20
#define CB1 NC0
#define CB2 (NC0 + NC1)
#define CB3 (NC0 + NC1 + NC2)
#define NC_TOT (NC0 + NC1 + NC2 + NC3)   // 471
#define NBIN 512
#define BATCH 8192
#define NCHUNK ((E_TOT + BATCH - 1) / BATCH)

typedef __attribute__((ext_vector_type(8))) short short8v;
typedef __attribute__((ext_vector_type(4))) float f32x4;

// ---------------- bf16 helpers ----------------

__device__ __forceinline__ unsigned bf16rn(float a) {
    unsigned ua = __float_as_uint(a);
    return (ua + 0x7fffu + ((ua >> 16) & 1u)) >> 16;
}

__device__ __forceinline__ void fma8(float* a, float w, uint4 u) {
    a[0] += w * __uint_as_float(u.x << 16);
    a[1] += w * __uint_as_float(u.x & 0xffff0000u);
    a[2] += w * __uint_as_float(u.y << 16);
    a[3] += w * __uint_as_float(u.y & 0xffff0000u);
    a[4] += w * __uint_as_float(u.z << 16);
    a[5] += w * __uint_as_float(u.z & 0xffff0000u);
    a[6] += w * __uint_as_float(u.w << 16);
    a[7] += w * __uint_as_float(u.w & 0xffff0000u);
}

// ---------------- CSR build ----------------

__global__ __launch_bounds__(256) void coarse_count(
        const int* __restrict__ d0, const int* __restrict__ d1,
        const int* __restrict__ d2, const int* __restrict__ d3,
        int* __restrict__ ccnt) {
    __shared__ int h[NBIN];
    for (int b = threadIdx.x; b < NBIN; b += 256) h[b] = 0;
    __syncthreads();
    int stride = gridDim.x * blockDim.x;
    for (int gi = blockIdx.x * blockDim.x + threadIdx.x; gi < E_TOT; gi += stride) {
        int bin;
        if (gi < B1)      bin = d0[gi] >> CSH0;
        else if (gi < B2) bin = CB1 + (d1[gi - B1] >> CSH1);
        else if (gi < B3) bin = CB2 + (d2[gi - B2] >> CSH2);
        else              bin = CB3 + (d3[gi - B3] >> CSH3);
        atomicAdd(&h[bin], 1);
    }
    __syncthreads();
    for (int b = threadIdx.x; b < NC_TOT; b += 256) {
        int v = h[b];
        if (v) atomicAdd(&ccnt[b], v);
    }
}

__global__ __launch_bounds__(512) void cscan(const int* __restrict__ ccnt,
                                             int* __restrict__ gb,
                                             int* __restrict__ gcur) {
    __shared__ int sh[512];
    int t = threadIdx.x;
    int c = (t < NC_TOT) ? ccnt[t] : 0;
    sh[t] = c;
    __syncthreads();
    for (int off = 1; off < 512; off <<= 1) {
        int v = (t >= off) ? sh[t - off] : 0;
        __syncthreads();
        sh[t] += v;
        __syncthreads();
    }
    if (t < NC_TOT) {
        int excl = sh[t] - c;
        int pre, gbase;
        if (t < CB1)      { pre = 0;           gbase = 0;  }
        else if (t < CB2) { pre = sh[CB1 - 1]; gbase = B1; }
        else if (t < CB3) { pre = sh[CB2 - 1]; gbase = B2; }
        else              { pre = sh[CB3 - 1]; gbase = B3; }
        int wb = excl - pre;
        gb[t] = wb;
        gcur[t] = gbase + wb;
    }
}

__global__ __launch_bounds__(256) void binA(
        const int* __restrict__ d0, const int* __restrict__ s0, const float* __restrict__ v0,
        const int* __restrict__ d1, const int* __restrict__ s1, const float* __restrict__ v1,
        const int* __restrict__ d2, const int* __restrict__ s2, const float* __restrict__ v2,
        const int* __restrict__ d3, const int* __restrict__ s3, const float* __restrict__ v3,
        int* __restrict__ gcur, int2* __restrict__ stage) {
    __shared__ int2 buf[BATCH];
    __shared__ int hist[NBIN];
    __shared__ int scx[NBIN];
    __shared__ int cur[NBIN];
    __shared__ int obase[NBIN];
    int tid = threadIdx.x;
    int e0 = blockIdx.x * BATCH;
    int e1 = min(E_TOT, e0 + BATCH);

    for (int b = tid; b < NBIN; b += 256) hist[b] = 0;
    __syncthreads();

    for (int i = e0 + tid; i < e1; i += 256) {
        int bin;
        if (i < B1)      bin = d0[i] >> CSH0;
        else if (i < B2) bin = CB1 + (d1[i - B1] >> CSH1);
        else if (i < B3) bin = CB2 + (d2[i - B2] >> CSH2);
        else             bin = CB3 + (d3[i - B3] >> CSH3);
        atomicAdd(&hist[bin], 1);
    }
    __syncthreads();

    for (int b = tid; b < NBIN; b += 256) scx[b] = hist[b];
    __syncthreads();
    for (int off = 1; off < NBIN; off <<= 1) {
        int i0 = tid, i1 = tid + 256;
        int t0 = (i0 >= off) ? scx[i0 - off] : 0;
        int t1 = (i1 >= off) ? scx[i1 - off] : 0;
        __syncthreads();
        scx[i0] += t0;
        scx[i1] += t1;
        __syncthreads();
    }
    for (int b = tid; b < NBIN; b += 256) {
        int h = hist[b];
        int ex = scx[b] - h;
        scx[b] = ex;
        cur[b] = ex;
        if (h > 0) obase[b] = atomicAdd(&gcur[b], h);
    }
    __syncthreads();

    for (int i = e0 + tid; i < e1; i += 256) {
        int bin; int2 rec;
        if (i < B1) {
            int li = i;      int d = d0[li];
            rec.x = s0[li] | ((d & ((1 << CSH0) - 1)) << 17);
            rec.y = __float_as_int(v0[li]);
            bin = d >> CSH0;
        } else if (i < B2) {
            int li = i - B1; int d = d1[li];
            rec.x = s1[li] | ((d & ((1 << CSH1) - 1)) << 17);
            rec.y = __float_as_int(v1[li]);
            bin = CB1 + (d >> CSH1);
        } else if (i < B3) {
            int li = i - B2; int d = d2[li];
            rec.x = s2[li] | ((d & ((1 << CSH2) - 1)) << 17);
            rec.y = __float_as_int(v2[li]);
            bin = CB2 + (d >> CSH2);
        } else {
            int li = i - B3; int d = d3[li];
            rec.x = s3[li] | ((d & ((1 << CSH3) - 1)) << 17);
            rec.y = __float_as_int(v3[li]);
            bin = CB3 + (d >> CSH3);
        }
        int p = atomicAdd(&cur[bin], 1);
        buf[p] = rec;
    }
    __syncthreads();

    int cntE = e1 - e0;
    for (int j = tid; j < cntE; j += 256) {
        int lo = 0, hi = NBIN - 1;
        while (lo < hi) {
            int mid = (lo + hi + 1) >> 1;
            if (scx[mid] <= j) lo = mid; else hi = mid - 1;
        }
        stage[obase[lo] + (j - scx[lo])] = buf[j];
    }
}

__global__ __launch_bounds__(512) void binB(
        int* __restrict__ r0, int* __restrict__ r1,
        int* __restrict__ r2, int* __restrict__ r3,
        int2* __restrict__ e0, int2* __restrict__ e1,
        int2* __restrict__ e2, int2* __restrict__ e3,
        const int* __restrict__ gb, const int2* __restrict__ stage) {
    __shared__ int lc[1024];
    __shared__ int lcur[1024];
    int b = blockIdx.x;
    int* rp; int2* eo; int n, k, csh, ebase, Eg, nbEnd;
    if (b < CB1)       { k = b;       rp = r0; eo = e0; n = N_U; csh = CSH0; ebase = 0;  Eg = E_UB; nbEnd = CB1;    }
    else if (b < CB2)  { k = b - CB1; rp = r1; eo = e1; n = N_U; csh = CSH1; ebase = B1; Eg = E_UU; nbEnd = CB2;    }
    else if (b < CB3)  { k = b - CB2; rp = r2; eo = e2; n = N_B; csh = CSH2; ebase = B2; Eg = E_UB; nbEnd = CB3;    }
    else               { k = b - CB3; rp = r3; eo = e3; n = N_B; csh = CSH3; ebase = B3; Eg = E_BB; nbEnd = NC_TOT; }
    int lo = k << csh;
    int hi = min(n, lo + (1 << csh));
    int rows = hi - lo;
    int base = gb[b];
    int cnt = ((b + 1 < nbEnd) ? gb[b + 1] : Eg) - base;
    const int2* sp = stage + ebase + base;

    for (int j = threadIdx.x; j < 1024; j += 512) lc[j] = 0;
    __syncthreads();
    for (int i = threadIdx.x; i < cnt; i += 512)
        atomicAdd(&lc[((unsigned)sp[i].x) >> 17], 1);
    __syncthreads();
    for (int off = 1; off < 1024; off <<= 1) {
        int i0 = threadIdx.x, i1 = threadIdx.x + 512;
        int t0 = (i0 >= off) ? lc[i0 - off] : 0;
        int t1 = (i1 >= off) ? lc[i1 - off] : 0;
        __syncthreads();
        lc[i0] += t0;
        lc[i1] += t1;
        __syncthreads();
    }
    for (int j = threadIdx.x; j < rows; j += 512) {
        int ex = base + ((j > 0) ? lc[j - 1] : 0);
        rp[lo + j] = ex;
        lcur[j] = ex;
    }
    if (threadIdx.x == 0 && hi == n) rp[n] = Eg;
    __syncthreads();
    for (int i = threadIdx.x; i < cnt; i += 512) {
        int2 rec = sp[i];
        int p = atomicAdd(&lcur[((unsigned)rec.x) >> 17], 1);
        eo[p] = make_int2(rec.x & 0x1FFFF, rec.y);
    }
}

// ---------------- dense projection via MFMA (error-compensated bf16 split) ----------------
// W[384][128] fp32 -> transposed hi/lo bf16 Wt[128][384]; x*w = xh*wh + xl*wh + xh*wl
// (dropped xl*wl term is ~2^-18 relative -> fp32-equivalent accuracy).

__global__ __launch_bounds__(256) void convW(const float* __restrict__ Wu, const float* __restrict__ Wb,
                                             short* __restrict__ Wuh, short* __restrict__ Wul,
                                             short* __restrict__ Wbh, short* __restrict__ Wbl) {
    int i = blockIdx.x * 256 + threadIdx.x;
    if (i >= 2 * IN_DIM * D) return;
    int m = i / (IN_DIM * D);
    int j = i - m * (IN_DIM * D);
    int k = j / D, n = j - k * D;
    float x = (m ? Wb : Wu)[j];
    unsigned h = bf16rn(x);
    unsigned lb = bf16rn(x - __uint_as_float(h << 16));
    (m ? Wbh : Wuh)[n * IN_DIM + k] = (short)h;
    (m ? Wbl : Wul)[n * IN_DIM + k] = (short)lb;
}

// block: 32 rows x 128 cols, 4 waves (wave = 16 rows x 64 cols = 4 col-tiles x 12 k-steps).
// X tile staged in LDS as hi/lo bf16, XOR-swizzled ((row&7)<<4) for conflict-free
// ds_read_b128 fragment loads. B fragments read from L2-resident transposed W.
__global__ __launch_bounds__(256) void gemm_mfma(
        const float* __restrict__ X, const short* __restrict__ Wth, const short* __restrict__ Wtl,
        unsigned short* __restrict__ curh, float* __restrict__ sum) {
    __shared__ __align__(16) short Ah[32 * IN_DIM];
    __shared__ __align__(16) short Al[32 * IN_DIM];
    int mBase = blockIdx.x * 32;
    const float4* Xv = (const float4*)X;
#pragma unroll
    for (int i = 0; i < 12; ++i) {
        int idx = i * 256 + threadIdx.x;      // 0..3071
        int row = idx / 96;
        int kq = idx - row * 96;              // float4 index within row
        float4 v = Xv[(size_t)(mBase + row) * 96 + kq];
        unsigned h0 = bf16rn(v.x), h1 = bf16rn(v.y), h2 = bf16rn(v.z), h3 = bf16rn(v.w);
        unsigned l0 = bf16rn(v.x - __uint_as_float(h0 << 16));
        unsigned l1 = bf16rn(v.y - __uint_as_float(h1 << 16));
        unsigned l2 = bf16rn(v.z - __uint_as_float(h2 << 16));
        unsigned l3 = bf16rn(v.w - __uint_as_float(h3 << 16));
        int byte = (row * 768 + kq * 8) ^ ((row & 7) << 4);
        *(uint2*)((char*)Ah + byte) = make_uint2(h0 | (h1 << 16), h2 | (h3 << 16));
        *(uint2*)((char*)Al + byte) = make_uint2(l0 | (l1 << 16), l2 | (l3 << 16));
    }
    __syncthreads();

    int l = threadIdx.x & 63, w = threadIdx.x >> 6;
    int rows16 = (w & 1) << 4;
    int cols0 = (w >> 1) << 6;
    int lr = l & 15, lg = l >> 4;
    f32x4 acc[4];
#pragma unroll
    for (int c = 0; c < 4; ++c) acc[c] = (f32x4){0.f, 0.f, 0.f, 0.f};
    int arow = rows16 + lr;
    int aswz = (arow & 7) << 4;
    const short* wh0 = Wth + (cols0 + lr) * IN_DIM + lg * 8;
    const short* wl0 = Wtl + (cols0 + lr) * IN_DIM + lg * 8;
#pragma unroll
    for (int ks = 0; ks < 12; ++ks) {
        int abyte = (arow * 768 + ks * 64 + lg * 16) ^ aswz;
        short8v ah = *(const short8v*)((const char*)Ah + abyte);
        short8v al = *(const short8v*)((const char*)Al + abyte);
#pragma unroll
        for (int ct = 0; ct < 4; ++ct) {
            short8v bh = *(const short8v*)(wh0 + ct * (16 * IN_DIM) + ks * 32);
            short8v bl = *(const short8v*)(wl0 + ct * (16 * IN_DIM) + ks * 32);
            acc[ct] = __builtin_amdgcn_mfma_f32_16x16x32_bf16(ah, bh, acc[ct], 0, 0, 0);
            acc[ct] = __builtin_amdgcn_mfma_f32_16x16x32_bf16(al, bh, acc[ct], 0, 0, 0);
            acc[ct] = __builtin_amdgcn_mfma_f32_16x16x32_bf16(ah, bl, acc[ct], 0, 0, 0);
        }
    }
    // C/D layout: col = lane&15, row = (lane>>4)*4 + reg  [HW-verified mapping]
#pragma unroll
    for (int ct = 0; ct < 4; ++ct) {
        int col = cols0 + ct * 16 + lr;
#pragma unroll
        for (int r = 0; r < 4; ++r) {
            int row = mBase + rows16 + lg * 4 + r;
            float v = acc[ct][r];
            size_t o = (size_t)row * D + col;
            sum[o] = v;
            curh[o] = (unsigned short)bf16rn(v);
        }
    }
}

// ---------------- fused pull SpMM ----------------

__global__ void spmm_fused(const int* __restrict__ rp1, const int2* __restrict__ e1,
                           const int* __restrict__ rp2, const int2* __restrict__ e2,
                           const uint4* __restrict__ x1, const uint4* __restrict__ x2,
                           uint4* __restrict__ y_nxt, float4* __restrict__ sum, int n) {
    int wave = threadIdx.x >> 6;
    int lane = threadIdx.x & 63;
    int q = lane >> 4;
    int l = lane & 15;
    int r = blockIdx.x * 4 + wave;
    if (r >= n) return;

    float acc[8];
#pragma unroll
    for (int k = 0; k < 8; ++k) acc[k] = 0.f;

#pragma unroll
    for (int pass = 0; pass < 2; ++pass) {
        const int* rp = pass ? rp2 : rp1;
        const int2* edges = pass ? e2 : e1;
        const uint4* xv = pass ? x2 : x1;
        int s = rp[r], e = rp[r + 1];
        int i = s;
        for (; i + 8 <= e; i += 8) {
            int2 edA = edges[i + q];
            int2 edB = edges[i + 4 + q];
            uint4 uA = xv[(size_t)edA.x * 16 + l];
            uint4 uB = xv[(size_t)edB.x * 16 + l];
            fma8(acc, __int_as_float(edA.y), uA);
            fma8(acc, __int_as_float(edB.y), uB);
        }
        if (i < e) {
            int idx = i + q;
            bool valid = idx < e;
            int2 ed = edges[valid ? idx : (e - 1)];
            uint4 u = xv[(size_t)ed.x * 16 + l];
            fma8(acc, valid ? __int_as_float(ed.y) : 0.f, u);
            i += 4;
            if (i < e) {
                idx = i + q;
                valid = idx < e;
                int2 ed2 = edges[valid ? idx : (e - 1)];
                uint4 u2 = xv[(size_t)ed2.x * 16 + l];
                fma8(acc, valid ? __int_as_float(ed2.y) : 0.f, u2);
            }
        }
    }

#pragma unroll
    for (int k = 0; k < 8; ++k) {
        acc[k] += __shfl_xor(acc[k], 16);
        acc[k] += __shfl_xor(acc[k], 32);
    }

    if (q == 0) {
        uint4 p;
        p.x = bf16rn(acc[0]) | (bf16rn(acc[1]) << 16);
        p.y = bf16rn(acc[2]) | (bf16rn(acc[3]) << 16);
        p.z = bf16rn(acc[4]) | (bf16rn(acc[5]) << 16);
        p.w = bf16rn(acc[6]) | (bf16rn(acc[7]) << 16);
        y_nxt[(size_t)r * 16 + l] = p;
        float4* sp = sum + (size_t)r * 32 + 2 * l;
        float4 s0 = sp[0], s1 = sp[1];
        s0.x += acc[0]; s0.y += acc[1]; s0.z += acc[2]; s0.w += acc[3];
        s1.x += acc[4]; s1.y += acc[5]; s1.z += acc[6]; s1.w += acc[7];
        sp[0] = s0; sp[1] = s1;
    }
}

// ---------------- normalize ----------------

__global__ void norm_kernel(float* __restrict__ out, int n) {
    int wave = threadIdx.x >> 6;
    int lane = threadIdx.x & 63;
    int r = blockIdx.x * 4 + wave;
    if (r >= n) return;
    float2* p = (float2*)out + (size_t)r * 64 + lane;
    float2 v = *p;
    v.x *= 0.25f;
    v.y *= 0.25f;
    float ss = v.x * v.x + v.y * v.y;
    for (int off = 32; off > 0; off >>= 1) ss += __shfl_down(ss, off);
    ss = __shfl(ss, 0);
    float inv = 1.f / fmaxf(sqrtf(ss), 1e-12f);
    v.x *= inv;
    v.y *= inv;
    *p = v;
}

// ---------------- launch ----------------

extern "C" void kernel_launch(void* const* d_in, const int* in_sizes, int n_in,
                              void* d_out, int out_size, void* d_ws, size_t ws_size,
                              hipStream_t stream) {
    const float* user_feat = (const float*)d_in[0];
    const float* biz_feat  = (const float*)d_in[1];
    const float* W_user    = (const float*)d_in[2];
    const float* W_biz     = (const float*)d_in[3];
    const int*   ub_u      = (const int*)d_in[4];
    const int*   ub_b      = (const int*)d_in[5];
    const float* val_ub    = (const float*)d_in[6];
    const float* val_bu    = (const float*)d_in[7];
    const int*   uu_src    = (const int*)d_in[8];
    const int*   uu_dst    = (const int*)d_in[9];
    const float* uu_val    = (const float*)d_in[10];
    const int*   bb_src    = (const int*)d_in[11];
    const int*   bb_dst    = (const int*)d_in[12];
    const float* bb_val    = (const float*)d_in[13];

    float* out   = (float*)d_out;
    float* u_sum = out;
    float* b_sum = out + (size_t)N_U * D;

    char* ws = (char*)d_ws;
    size_t off = 0;
    auto alloc = [&](size_t bytes) -> void* {
        void* p = ws + off;
        off += (bytes + 255) & ~(size_t)255;
        return p;
    };
    unsigned* u_curh = (unsigned*)alloc((size_t)N_U * 64 * 4);   // bf16 [N_U,128]
    unsigned* b_curh = (unsigned*)alloc((size_t)N_B * 64 * 4);
    int2* e_bu = (int2*)alloc((size_t)E_UB * 8);
    int2* e_uu = (int2*)alloc((size_t)E_UU * 8);
    int2* e_ub = (int2*)alloc((size_t)E_UB * 8);
    int2* e_bb = (int2*)alloc((size_t)E_BB * 8);
    int*  ccnt = (int*)alloc(NC_TOT * 4);
    int*  gb   = (int*)alloc(NC_TOT * 4);
    int*  gcur = (int*)alloc(NC_TOT * 4);
    int*  rp_bu = (int*)alloc((N_U + 1) * 4);
    int*  rp_uu = (int*)alloc((N_U + 1) * 4);
    int*  rp_ub = (int*)alloc((N_B + 1) * 4);
    int*  rp_bb = (int*)alloc((N_B + 1) * 4);
    short* Wuh = (short*)alloc((size_t)D * IN_DIM * 2);
    short* Wul = (short*)alloc((size_t)D * IN_DIM * 2);
    short* Wbh = (short*)alloc((size_t)D * IN_DIM * 2);
    short* Wbl = (short*)alloc((size_t)D * IN_DIM * 2);
    // staging region; u_nxth/b_nxth alias its head (used only after binB completes)
    int2* stage = (int2*)alloc((size_t)E_TOT * 8);
    unsigned* u_nxth = (unsigned*)stage;
    unsigned* b_nxth = (unsigned*)((char*)stage + (size_t)N_U * 64 * 4);

    hipMemsetAsync(ccnt, 0, sizeof(int) * NC_TOT, stream);

    coarse_count<<<1024, 256, 0, stream>>>(ub_u, uu_dst, ub_b, bb_dst, ccnt);
    cscan<<<1, 512, 0, stream>>>(ccnt, gb, gcur);
    binA<<<NCHUNK, 256, 0, stream>>>(ub_u,   ub_b,   val_bu,
                                     uu_dst, uu_src, uu_val,
                                     ub_b,   ub_u,   val_ub,
                                     bb_dst, bb_src, bb_val,
                                     gcur, stage);
    binB<<<NC_TOT, 512, 0, stream>>>(rp_bu, rp_uu, rp_ub, rp_bb,
                                     e_bu, e_uu, e_ub, e_bb, gb, stage);

    convW<<<(2 * IN_DIM * D + 255) / 256, 256, 0, stream>>>(W_user, W_biz, Wuh, Wul, Wbh, Wbl);
    gemm_mfma<<<N_U / 32, 256, 0, stream>>>(user_feat, Wuh, Wul, (unsigned short*)u_curh, u_sum);
    gemm_mfma<<<N_B / 32, 256, 0, stream>>>(biz_feat,  Wbh, Wbl, (unsigned short*)b_curh, b_sum);

    for (int l = 0; l < 3; ++l) {
        spmm_fused<<<(N_U + 3) / 4, 256, 0, stream>>>(rp_bu, e_bu, rp_uu, e_uu,
                                                      (const uint4*)b_curh, (const uint4*)u_curh,
                                                      (uint4*)u_nxth, (float4*)u_sum, N_U);
        spmm_fused<<<(N_B + 3) / 4, 256, 0, stream>>>(rp_ub, e_ub, rp_bb, e_bb,
                                                      (const uint4*)u_curh, (const uint4*)b_curh,
                                                      (uint4*)b_nxth, (float4*)b_sum, N_B);
        unsigned* t;
        t = u_curh; u_curh = u_nxth; u_nxth = t;
        t = b_curh; b_curh = b_nxth; b_nxth = t;
    }

    norm_kernel<<<(N_U + 3) / 4, 256, 0, stream>>>(u_sum, N_U);
    norm_kernel<<<(N_B + 3) / 4, 256, 0, stream>>>(b_sum, N_B);
}

// Round 4
// 1418.943 us; speedup vs baseline: 1.8576x; 1.0773x over previous
//
#include <hip/hip_runtime.h>

#define N_U 100000
#define N_B 20000
#define E_UB 3200000
#define E_UU 1600000
#define E_BB 320000
#define IN_DIM 384
#define D 128

// graph order: 0=bu (dst=ub_u), 1=uu (dst=uu_dst), 2=ub (dst=ub_b), 3=bb (dst=bb_dst)
#define B1 E_UB
#define B2 (E_UB + E_UU)
#define B3 (E_UB + E_UU + E_UB)
#define E_TOT (E_UB + E_UU + E_UB + E_BB)

// ---- coarse bins for the two-level LDS-presorted build ----
#define CSH0 9
#define CSH1 10
#define CSH2 7
#define CSH3 10
#define NC0 196
#define NC1 98
#define NC2 157
#define NC3 20
#define CB1 NC0
#define CB2 (NC0 + NC1)
#define CB3 (NC0 + NC1 + NC2)
#define NC_TOT (NC0 + NC1 + NC2 + NC3)   // 471
#define NBIN 512
#define BATCH 8192
#define NCHUNK ((E_TOT + BATCH - 1) / BATCH)

// waves (32 rows each) in the fused gemm dispatch
#define NW_U (N_U / 32)     // 3125
#define NW_B (N_B / 32)     // 625

typedef __attribute__((ext_vector_type(8))) short short8v;
typedef __attribute__((ext_vector_type(4))) float f32x4;

// ---------------- bf16 helpers ----------------

__device__ __forceinline__ unsigned bf16rn(float a) {
    unsigned ua = __float_as_uint(a);
    return (ua + 0x7fffu + ((ua >> 16) & 1u)) >> 16;
}

__device__ __forceinline__ void fma8(float* a, float w, uint4 u) {
    a[0] += w * __uint_as_float(u.x << 16);
    a[1] += w * __uint_as_float(u.x & 0xffff0000u);
    a[2] += w * __uint_as_float(u.y << 16);
    a[3] += w * __uint_as_float(u.y & 0xffff0000u);
    a[4] += w * __uint_as_float(u.z << 16);
    a[5] += w * __uint_as_float(u.z & 0xffff0000u);
    a[6] += w * __uint_as_float(u.w << 16);
    a[7] += w * __uint_as_float(u.w & 0xffff0000u);
}

// 8 consecutive fp32 -> bf16 hi (RNE) + lo (trunc; 2^-17-scale term, trunc is plenty)
__device__ __forceinline__ void cvt8(float4 a, float4 b, short8v& h, short8v& lo) {
    float f[8] = {a.x, a.y, a.z, a.w, b.x, b.y, b.z, b.w};
#pragma unroll
    for (int i = 0; i < 8; ++i) {
        unsigned hb = bf16rn(f[i]);
        h[i] = (short)hb;
        float r = f[i] - __uint_as_float(hb << 16);
        lo[i] = (short)(__float_as_uint(r) >> 16);
    }
}

// ---------------- CSR build ----------------

__global__ __launch_bounds__(256) void coarse_count(
        const int* __restrict__ d0, const int* __restrict__ d1,
        const int* __restrict__ d2, const int* __restrict__ d3,
        int* __restrict__ ccnt) {
    __shared__ int h[NBIN];
    for (int b = threadIdx.x; b < NBIN; b += 256) h[b] = 0;
    __syncthreads();
    int stride = gridDim.x * blockDim.x;
    for (int gi = blockIdx.x * blockDim.x + threadIdx.x; gi < E_TOT; gi += stride) {
        int bin;
        if (gi < B1)      bin = d0[gi] >> CSH0;
        else if (gi < B2) bin = CB1 + (d1[gi - B1] >> CSH1);
        else if (gi < B3) bin = CB2 + (d2[gi - B2] >> CSH2);
        else              bin = CB3 + (d3[gi - B3] >> CSH3);
        atomicAdd(&h[bin], 1);
    }
    __syncthreads();
    for (int b = threadIdx.x; b < NC_TOT; b += 256) {
        int v = h[b];
        if (v) atomicAdd(&ccnt[b], v);
    }
}

__global__ __launch_bounds__(512) void cscan(const int* __restrict__ ccnt,
                                             int* __restrict__ gb,
                                             int* __restrict__ gcur) {
    __shared__ int sh[512];
    int t = threadIdx.x;
    int c = (t < NC_TOT) ? ccnt[t] : 0;
    sh[t] = c;
    __syncthreads();
    for (int off = 1; off < 512; off <<= 1) {
        int v = (t >= off) ? sh[t - off] : 0;
        __syncthreads();
        sh[t] += v;
        __syncthreads();
    }
    if (t < NC_TOT) {
        int excl = sh[t] - c;
        int pre, gbase;
        if (t < CB1)      { pre = 0;           gbase = 0;  }
        else if (t < CB2) { pre = sh[CB1 - 1]; gbase = B1; }
        else if (t < CB3) { pre = sh[CB2 - 1]; gbase = B2; }
        else              { pre = sh[CB3 - 1]; gbase = B3; }
        int wb = excl - pre;
        gb[t] = wb;
        gcur[t] = gbase + wb;
    }
}

__global__ __launch_bounds__(256) void binA(
        const int* __restrict__ d0, const int* __restrict__ s0, const float* __restrict__ v0,
        const int* __restrict__ d1, const int* __restrict__ s1, const float* __restrict__ v1,
        const int* __restrict__ d2, const int* __restrict__ s2, const float* __restrict__ v2,
        const int* __restrict__ d3, const int* __restrict__ s3, const float* __restrict__ v3,
        int* __restrict__ gcur, int2* __restrict__ stage) {
    __shared__ int2 buf[BATCH];
    __shared__ int hist[NBIN];
    __shared__ int scx[NBIN];
    __shared__ int cur[NBIN];
    __shared__ int obase[NBIN];
    int tid = threadIdx.x;
    int e0 = blockIdx.x * BATCH;
    int e1 = min(E_TOT, e0 + BATCH);

    for (int b = tid; b < NBIN; b += 256) hist[b] = 0;
    __syncthreads();

    for (int i = e0 + tid; i < e1; i += 256) {
        int bin;
        if (i < B1)      bin = d0[i] >> CSH0;
        else if (i < B2) bin = CB1 + (d1[i - B1] >> CSH1);
        else if (i < B3) bin = CB2 + (d2[i - B2] >> CSH2);
        else             bin = CB3 + (d3[i - B3] >> CSH3);
        atomicAdd(&hist[bin], 1);
    }
    __syncthreads();

    for (int b = tid; b < NBIN; b += 256) scx[b] = hist[b];
    __syncthreads();
    for (int off = 1; off < NBIN; off <<= 1) {
        int i0 = tid, i1 = tid + 256;
        int t0 = (i0 >= off) ? scx[i0 - off] : 0;
        int t1 = (i1 >= off) ? scx[i1 - off] : 0;
        __syncthreads();
        scx[i0] += t0;
        scx[i1] += t1;
        __syncthreads();
    }
    for (int b = tid; b < NBIN; b += 256) {
        int h = hist[b];
        int ex = scx[b] - h;
        scx[b] = ex;
        cur[b] = ex;
        if (h > 0) obase[b] = atomicAdd(&gcur[b], h);
    }
    __syncthreads();

    for (int i = e0 + tid; i < e1; i += 256) {
        int bin; int2 rec;
        if (i < B1) {
            int li = i;      int d = d0[li];
            rec.x = s0[li] | ((d & ((1 << CSH0) - 1)) << 17);
            rec.y = __float_as_int(v0[li]);
            bin = d >> CSH0;
        } else if (i < B2) {
            int li = i - B1; int d = d1[li];
            rec.x = s1[li] | ((d & ((1 << CSH1) - 1)) << 17);
            rec.y = __float_as_int(v1[li]);
            bin = CB1 + (d >> CSH1);
        } else if (i < B3) {
            int li = i - B2; int d = d2[li];
            rec.x = s2[li] | ((d & ((1 << CSH2) - 1)) << 17);
            rec.y = __float_as_int(v2[li]);
            bin = CB2 + (d >> CSH2);
        } else {
            int li = i - B3; int d = d3[li];
            rec.x = s3[li] | ((d & ((1 << CSH3) - 1)) << 17);
            rec.y = __float_as_int(v3[li]);
            bin = CB3 + (d >> CSH3);
        }
        int p = atomicAdd(&cur[bin], 1);
        buf[p] = rec;
    }
    __syncthreads();

    int cntE = e1 - e0;
    for (int j = tid; j < cntE; j += 256) {
        int lo = 0, hi = NBIN - 1;
        while (lo < hi) {
            int mid = (lo + hi + 1) >> 1;
            if (scx[mid] <= j) lo = mid; else hi = mid - 1;
        }
        stage[obase[lo] + (j - scx[lo])] = buf[j];
    }
}

__global__ __launch_bounds__(512) void binB(
        int* __restrict__ r0, int* __restrict__ r1,
        int* __restrict__ r2, int* __restrict__ r3,
        int2* __restrict__ e0, int2* __restrict__ e1,
        int2* __restrict__ e2, int2* __restrict__ e3,
        const int* __restrict__ gb, const int2* __restrict__ stage) {
    __shared__ int lc[1024];
    __shared__ int lcur[1024];
    int b = blockIdx.x;
    int* rp; int2* eo; int n, k, csh, ebase, Eg, nbEnd;
    if (b < CB1)       { k = b;       rp = r0; eo = e0; n = N_U; csh = CSH0; ebase = 0;  Eg = E_UB; nbEnd = CB1;    }
    else if (b < CB2)  { k = b - CB1; rp = r1; eo = e1; n = N_U; csh = CSH1; ebase = B1; Eg = E_UU; nbEnd = CB2;    }
    else if (b < CB3)  { k = b - CB2; rp = r2; eo = e2; n = N_B; csh = CSH2; ebase = B2; Eg = E_UB; nbEnd = CB3;    }
    else               { k = b - CB3; rp = r3; eo = e3; n = N_B; csh = CSH3; ebase = B3; Eg = E_BB; nbEnd = NC_TOT; }
    int lo = k << csh;
    int hi = min(n, lo + (1 << csh));
    int rows = hi - lo;
    int base = gb[b];
    int cnt = ((b + 1 < nbEnd) ? gb[b + 1] : Eg) - base;
    const int2* sp = stage + ebase + base;

    for (int j = threadIdx.x; j < 1024; j += 512) lc[j] = 0;
    __syncthreads();
    for (int i = threadIdx.x; i < cnt; i += 512)
        atomicAdd(&lc[((unsigned)sp[i].x) >> 17], 1);
    __syncthreads();
    for (int off = 1; off < 1024; off <<= 1) {
        int i0 = threadIdx.x, i1 = threadIdx.x + 512;
        int t0 = (i0 >= off) ? lc[i0 - off] : 0;
        int t1 = (i1 >= off) ? lc[i1 - off] : 0;
        __syncthreads();
        lc[i0] += t0;
        lc[i1] += t1;
        __syncthreads();
    }
    for (int j = threadIdx.x; j < rows; j += 512) {
        int ex = base + ((j > 0) ? lc[j - 1] : 0);
        rp[lo + j] = ex;
        lcur[j] = ex;
    }
    if (threadIdx.x == 0 && hi == n) rp[n] = Eg;
    __syncthreads();
    for (int i = threadIdx.x; i < cnt; i += 512) {
        int2 rec = sp[i];
        int p = atomicAdd(&lcur[((unsigned)rec.x) >> 17], 1);
        eo[p] = make_int2(rec.x & 0x1FFFF, rec.y);
    }
}

// ---------------- dense projection via MFMA (error-compensated bf16 split) ----------------
// x*w = xh*wh + xl*wh + xh*wl (dropped xl*wl ~2^-17 relative -> fp32-equivalent here).
// W is pre-packed into MFMA B-fragment order: [ct(8)][ks(12)][lane(64)] x 16B, so the
// in-loop B load is one fully coalesced 1KB global_load_dwordx4 from L2-resident data.
// Fragment index mapping (HW-validated by the previous passing version):
//   lane l = lg*16+lr holds col = ct*16+lr, k = ks*32 + lg*8 .. +8.

__global__ __launch_bounds__(256) void convW(const float* __restrict__ Wu, const float* __restrict__ Wb,
                                             short* __restrict__ Wuh, short* __restrict__ Wul,
                                             short* __restrict__ Wbh, short* __restrict__ Wbl) {
    int i = blockIdx.x * 256 + threadIdx.x;
    if (i >= 2 * IN_DIM * D) return;
    int m = i / (IN_DIM * D);
    int j = i - m * (IN_DIM * D);
    int k = j / D, col = j - k * D;          // W[k][col], row-major [384][128]
    float x = (m ? Wb : Wu)[j];
    unsigned hb = bf16rn(x);
    unsigned lb = bf16rn(x - __uint_as_float(hb << 16));
    int ct = col >> 4, lr = col & 15, ks = k >> 5, lg = (k >> 3) & 3, e = k & 7;
    int oi = ((ct * 12 + ks) * 64 + (lg * 16 + lr)) * 8 + e;
    (m ? Wbh : Wuh)[oi] = (short)hb;
    (m ? Wbl : Wul)[oi] = (short)lb;
}

// One wave = 32 rows x 128 cols. No LDS, no barriers. A-fragments gathered per-lane
// straight from X (fp32) and split hi/lo in registers; 48 MFMAs per k-step vs 20 loads.
// user and biz fused into one dispatch (biz alone would underfill the grid).
__global__ __launch_bounds__(256) void gemm_mfma(
        const float* __restrict__ Xu, const float* __restrict__ Xb,
        const short* __restrict__ Wuh, const short* __restrict__ Wul,
        const short* __restrict__ Wbh, const short* __restrict__ Wbl,
        unsigned short* __restrict__ uch, float* __restrict__ usum,
        unsigned short* __restrict__ bch, float* __restrict__ bsum) {
    int l = threadIdx.x & 63, w = threadIdx.x >> 6;
    int wid = blockIdx.x * 4 + w;
    const float* X; const short *Wh, *Wl; unsigned short* ch; float* sm; int mBase;
    if (wid < NW_U) {
        X = Xu; Wh = Wuh; Wl = Wul; ch = uch; sm = usum; mBase = wid * 32;
    } else {
        int wb = wid - NW_U;
        if (wb >= NW_B) return;
        X = Xb; Wh = Wbh; Wl = Wbl; ch = bch; sm = bsum; mBase = wb * 32;
    }
    int lr = l & 15, lg = l >> 4;
    const float4* xr0 = (const float4*)(X + (size_t)(mBase + lr) * IN_DIM);
    const float4* xr1 = (const float4*)(X + (size_t)(mBase + 16 + lr) * IN_DIM);
    const short8v* bhp = (const short8v*)Wh + l;
    const short8v* blp = (const short8v*)Wl + l;

    f32x4 acc0[8], acc1[8];
#pragma unroll
    for (int ct = 0; ct < 8; ++ct) {
        acc0[ct] = (f32x4){0.f, 0.f, 0.f, 0.f};
        acc1[ct] = (f32x4){0.f, 0.f, 0.f, 0.f};
    }

#pragma unroll
    for (int ks = 0; ks < 12; ++ks) {
        float4 a0 = xr0[ks * 8 + lg * 2];
        float4 a1 = xr0[ks * 8 + lg * 2 + 1];
        float4 a2 = xr1[ks * 8 + lg * 2];
        float4 a3 = xr1[ks * 8 + lg * 2 + 1];
        short8v ah0, al0, ah1, al1;
        cvt8(a0, a1, ah0, al0);
        cvt8(a2, a3, ah1, al1);
#pragma unroll
        for (int ct = 0; ct < 8; ++ct) {
            short8v bh = bhp[(ct * 12 + ks) * 64];
            short8v bl = blp[(ct * 12 + ks) * 64];
            acc0[ct] = __builtin_amdgcn_mfma_f32_16x16x32_bf16(ah0, bh, acc0[ct], 0, 0, 0);
            acc1[ct] = __builtin_amdgcn_mfma_f32_16x16x32_bf16(ah1, bh, acc1[ct], 0, 0, 0);
            acc0[ct] = __builtin_amdgcn_mfma_f32_16x16x32_bf16(al0, bh, acc0[ct], 0, 0, 0);
            acc1[ct] = __builtin_amdgcn_mfma_f32_16x16x32_bf16(al1, bh, acc1[ct], 0, 0, 0);
            acc0[ct] = __builtin_amdgcn_mfma_f32_16x16x32_bf16(ah0, bl, acc0[ct], 0, 0, 0);
            acc1[ct] = __builtin_amdgcn_mfma_f32_16x16x32_bf16(ah1, bl, acc1[ct], 0, 0, 0);
        }
    }

    // C/D layout: col = lane&15, row = (lane>>4)*4 + reg  [HW-verified mapping]
#pragma unroll
    for (int ct = 0; ct < 8; ++ct) {
        int col = ct * 16 + lr;
#pragma unroll
        for (int r = 0; r < 4; ++r) {
            int row0 = mBase + lg * 4 + r;
            int row1 = mBase + 16 + lg * 4 + r;
            size_t o0 = (size_t)row0 * D + col;
            size_t o1 = (size_t)row1 * D + col;
            float v0 = acc0[ct][r], v1 = acc1[ct][r];
            sm[o0] = v0; ch[o0] = (unsigned short)bf16rn(v0);
            sm[o1] = v1; ch[o1] = (unsigned short)bf16rn(v1);
        }
    }
}

// ---------------- fused pull SpMM ----------------

__global__ void spmm_fused(const int* __restrict__ rp1, const int2* __restrict__ e1,
                           const int* __restrict__ rp2, const int2* __restrict__ e2,
                           const uint4* __restrict__ x1, const uint4* __restrict__ x2,
                           uint4* __restrict__ y_nxt, float4* __restrict__ sum, int n) {
    int wave = threadIdx.x >> 6;
    int lane = threadIdx.x & 63;
    int q = lane >> 4;
    int l = lane & 15;
    int r = blockIdx.x * 4 + wave;
    if (r >= n) return;

    float acc[8];
#pragma unroll
    for (int k = 0; k < 8; ++k) acc[k] = 0.f;

#pragma unroll
    for (int pass = 0; pass < 2; ++pass) {
        const int* rp = pass ? rp2 : rp1;
        const int2* edges = pass ? e2 : e1;
        const uint4* xv = pass ? x2 : x1;
        int s = rp[r], e = rp[r + 1];
        int i = s;
        for (; i + 8 <= e; i += 8) {
            int2 edA = edges[i + q];
            int2 edB = edges[i + 4 + q];
            uint4 uA = xv[(size_t)edA.x * 16 + l];
            uint4 uB = xv[(size_t)edB.x * 16 + l];
            fma8(acc, __int_as_float(edA.y), uA);
            fma8(acc, __int_as_float(edB.y), uB);
        }
        if (i < e) {
            int idx = i + q;
            bool valid = idx < e;
            int2 ed = edges[valid ? idx : (e - 1)];
            uint4 u = xv[(size_t)ed.x * 16 + l];
            fma8(acc, valid ? __int_as_float(ed.y) : 0.f, u);
            i += 4;
            if (i < e) {
                idx = i + q;
                valid = idx < e;
                int2 ed2 = edges[valid ? idx : (e - 1)];
                uint4 u2 = xv[(size_t)ed2.x * 16 + l];
                fma8(acc, valid ? __int_as_float(ed2.y) : 0.f, u2);
            }
        }
    }

#pragma unroll
    for (int k = 0; k < 8; ++k) {
        acc[k] += __shfl_xor(acc[k], 16);
        acc[k] += __shfl_xor(acc[k], 32);
    }

    if (q == 0) {
        uint4 p;
        p.x = bf16rn(acc[0]) | (bf16rn(acc[1]) << 16);
        p.y = bf16rn(acc[2]) | (bf16rn(acc[3]) << 16);
        p.z = bf16rn(acc[4]) | (bf16rn(acc[5]) << 16);
        p.w = bf16rn(acc[6]) | (bf16rn(acc[7]) << 16);
        y_nxt[(size_t)r * 16 + l] = p;
        float4* sp = sum + (size_t)r * 32 + 2 * l;
        float4 s0 = sp[0], s1 = sp[1];
        s0.x += acc[0]; s0.y += acc[1]; s0.z += acc[2]; s0.w += acc[3];
        s1.x += acc[4]; s1.y += acc[5]; s1.z += acc[6]; s1.w += acc[7];
        sp[0] = s0; sp[1] = s1;
    }
}

// ---------------- normalize ----------------

__global__ void norm_kernel(float* __restrict__ out, int n) {
    int wave = threadIdx.x >> 6;
    int lane = threadIdx.x & 63;
    int r = blockIdx.x * 4 + wave;
    if (r >= n) return;
    float2* p = (float2*)out + (size_t)r * 64 + lane;
    float2 v = *p;
    v.x *= 0.25f;
    v.y *= 0.25f;
    float ss = v.x * v.x + v.y * v.y;
    for (int off = 32; off > 0; off >>= 1) ss += __shfl_down(ss, off);
    ss = __shfl(ss, 0);
    float inv = 1.f / fmaxf(sqrtf(ss), 1e-12f);
    v.x *= inv;
    v.y *= inv;
    *p = v;
}

// ---------------- launch ----------------

extern "C" void kernel_launch(void* const* d_in, const int* in_sizes, int n_in,
                              void* d_out, int out_size, void* d_ws, size_t ws_size,
                              hipStream_t stream) {
    const float* user_feat = (const float*)d_in[0];
    const float* biz_feat  = (const float*)d_in[1];
    const float* W_user    = (const float*)d_in[2];
    const float* W_biz     = (const float*)d_in[3];
    const int*   ub_u      = (const int*)d_in[4];
    const int*   ub_b      = (const int*)d_in[5];
    const float* val_ub    = (const float*)d_in[6];
    const float* val_bu    = (const float*)d_in[7];
    const int*   uu_src    = (const int*)d_in[8];
    const int*   uu_dst    = (const int*)d_in[9];
    const float* uu_val    = (const float*)d_in[10];
    const int*   bb_src    = (const int*)d_in[11];
    const int*   bb_dst    = (const int*)d_in[12];
    const float* bb_val    = (const float*)d_in[13];

    float* out   = (float*)d_out;
    float* u_sum = out;
    float* b_sum = out + (size_t)N_U * D;

    char* ws = (char*)d_ws;
    size_t off = 0;
    auto alloc = [&](size_t bytes) -> void* {
        void* p = ws + off;
        off += (bytes + 255) & ~(size_t)255;
        return p;
    };
    unsigned* u_curh = (unsigned*)alloc((size_t)N_U * 64 * 4);   // bf16 [N_U,128]
    unsigned* b_curh = (unsigned*)alloc((size_t)N_B * 64 * 4);
    int2* e_bu = (int2*)alloc((size_t)E_UB * 8);
    int2* e_uu = (int2*)alloc((size_t)E_UU * 8);
    int2* e_ub = (int2*)alloc((size_t)E_UB * 8);
    int2* e_bb = (int2*)alloc((size_t)E_BB * 8);
    int*  ccnt = (int*)alloc(NC_TOT * 4);
    int*  gb   = (int*)alloc(NC_TOT * 4);
    int*  gcur = (int*)alloc(NC_TOT * 4);
    int*  rp_bu = (int*)alloc((N_U + 1) * 4);
    int*  rp_uu = (int*)alloc((N_U + 1) * 4);
    int*  rp_ub = (int*)alloc((N_B + 1) * 4);
    int*  rp_bb = (int*)alloc((N_B + 1) * 4);
    short* Wuh = (short*)alloc((size_t)D * IN_DIM * 2);
    short* Wul = (short*)alloc((size_t)D * IN_DIM * 2);
    short* Wbh = (short*)alloc((size_t)D * IN_DIM * 2);
    short* Wbl = (short*)alloc((size_t)D * IN_DIM * 2);
    // staging region; u_nxth/b_nxth alias its head (used only after binB completes)
    int2* stage = (int2*)alloc((size_t)E_TOT * 8);
    unsigned* u_nxth = (unsigned*)stage;
    unsigned* b_nxth = (unsigned*)((char*)stage + (size_t)N_U * 64 * 4);

    hipMemsetAsync(ccnt, 0, sizeof(int) * NC_TOT, stream);

    coarse_count<<<1024, 256, 0, stream>>>(ub_u, uu_dst, ub_b, bb_dst, ccnt);
    cscan<<<1, 512, 0, stream>>>(ccnt, gb, gcur);
    binA<<<NCHUNK, 256, 0, stream>>>(ub_u,   ub_b,   val_bu,
                                     uu_dst, uu_src, uu_val,
                                     ub_b,   ub_u,   val_ub,
                                     bb_dst, bb_src, bb_val,
                                     gcur, stage);
    binB<<<NC_TOT, 512, 0, stream>>>(rp_bu, rp_uu, rp_ub, rp_bb,
                                     e_bu, e_uu, e_ub, e_bb, gb, stage);

    convW<<<(2 * IN_DIM * D + 255) / 256, 256, 0, stream>>>(W_user, W_biz, Wuh, Wul, Wbh, Wbl);
    gemm_mfma<<<(NW_U + NW_B + 3) / 4, 256, 0, stream>>>(
        user_feat, biz_feat, Wuh, Wul, Wbh, Wbl,
        (unsigned short*)u_curh, u_sum, (unsigned short*)b_curh, b_sum);

    for (int l = 0; l < 3; ++l) {
        spmm_fused<<<(N_U + 3) / 4, 256, 0, stream>>>(rp_bu, e_bu, rp_uu, e_uu,
                                                      (const uint4*)b_curh, (const uint4*)u_curh,
                                                      (uint4*)u_nxth, (float4*)u_sum, N_U);
        spmm_fused<<<(N_B + 3) / 4, 256, 0, stream>>>(rp_ub, e_ub, rp_bb, e_bb,
                                                      (const uint4*)u_curh, (const uint4*)b_curh,
                                                      (uint4*)b_nxth, (float4*)b_sum, N_B);
        unsigned* t;
        t = u_curh; u_curh = u_nxth; u_nxth = t;
        t = b_curh; b_curh = b_nxth; b_nxth = t;
    }

    norm_kernel<<<(N_U + 3) / 4, 256, 0, stream>>>(u_sum, N_U);
    norm_kernel<<<(N_B + 3) / 4, 256, 0, stream>>>(b_sum, N_B);
}

// Round 6
// 1340.601 us; speedup vs baseline: 1.9662x; 1.0584x over previous
//
#include <hip/hip_runtime.h>

#define N_U 100000
#define N_B 20000
#define E_UB 3200000
#define E_UU 1600000
#define E_BB 320000
#define IN_DIM 384
#define D 128

// graph order: 0=bu (dst=ub_u), 1=uu (dst=uu_dst), 2=ub (dst=ub_b), 3=bb (dst=bb_dst)
#define B1 E_UB
#define B2 (E_UB + E_UU)
#define B3 (E_UB + E_UU + E_UB)
#define E_TOT (E_UB + E_UU + E_UB + E_BB)

// ---- coarse bins for the two-level LDS-presorted build ----
#define CSH0 9
#define CSH1 10
#define CSH2 7
#define CSH3 10
#define NC0 196
#define NC1 98
#define NC2 157
#define NC3 20
#define CB1 NC0
#define CB2 (NC0 + NC1)
#define CB3 (NC0 + NC1 + NC2)
#define NC_TOT (NC0 + NC1 + NC2 + NC3)   // 471
#define NBIN 512
#define BATCH 8192
#define NCHUNK ((E_TOT + BATCH - 1) / BATCH)

// waves (32 rows each) in the fused gemm dispatch
#define NW_U (N_U / 32)     // 3125
#define NW_B (N_B / 32)     // 625

typedef __attribute__((ext_vector_type(8))) short short8v;
typedef __attribute__((ext_vector_type(4))) float f32x4;

// ---------------- bf16 helpers ----------------

__device__ __forceinline__ unsigned bf16rn(float a) {
    unsigned ua = __float_as_uint(a);
    return (ua + 0x7fffu + ((ua >> 16) & 1u)) >> 16;
}

__device__ __forceinline__ void fma8(float* a, float w, uint4 u) {
    a[0] += w * __uint_as_float(u.x << 16);
    a[1] += w * __uint_as_float(u.x & 0xffff0000u);
    a[2] += w * __uint_as_float(u.y << 16);
    a[3] += w * __uint_as_float(u.y & 0xffff0000u);
    a[4] += w * __uint_as_float(u.z << 16);
    a[5] += w * __uint_as_float(u.z & 0xffff0000u);
    a[6] += w * __uint_as_float(u.w << 16);
    a[7] += w * __uint_as_float(u.w & 0xffff0000u);
}

// 8 consecutive fp32 -> bf16 hi (RNE) + lo (trunc; 2^-17-scale term, trunc is plenty)
__device__ __forceinline__ void cvt8(float4 a, float4 b, short8v& h, short8v& lo) {
    float f[8] = {a.x, a.y, a.z, a.w, b.x, b.y, b.z, b.w};
#pragma unroll
    for (int i = 0; i < 8; ++i) {
        unsigned hb = bf16rn(f[i]);
        h[i] = (short)hb;
        float r = f[i] - __uint_as_float(hb << 16);
        lo[i] = (short)(__float_as_uint(r) >> 16);
    }
}

// ---------------- CSR build ----------------

__global__ __launch_bounds__(256) void coarse_count(
        const int* __restrict__ d0, const int* __restrict__ d1,
        const int* __restrict__ d2, const int* __restrict__ d3,
        int* __restrict__ ccnt) {
    __shared__ int h[NBIN];
    for (int b = threadIdx.x; b < NBIN; b += 256) h[b] = 0;
    __syncthreads();
    int stride = gridDim.x * blockDim.x;
    for (int gi = blockIdx.x * blockDim.x + threadIdx.x; gi < E_TOT; gi += stride) {
        int bin;
        if (gi < B1)      bin = d0[gi] >> CSH0;
        else if (gi < B2) bin = CB1 + (d1[gi - B1] >> CSH1);
        else if (gi < B3) bin = CB2 + (d2[gi - B2] >> CSH2);
        else              bin = CB3 + (d3[gi - B3] >> CSH3);
        atomicAdd(&h[bin], 1);
    }
    __syncthreads();
    for (int b = threadIdx.x; b < NC_TOT; b += 256) {
        int v = h[b];
        if (v) atomicAdd(&ccnt[b], v);
    }
}

__global__ __launch_bounds__(512) void cscan(const int* __restrict__ ccnt,
                                             int* __restrict__ gb,
                                             int* __restrict__ gcur) {
    __shared__ int sh[512];
    int t = threadIdx.x;
    int c = (t < NC_TOT) ? ccnt[t] : 0;
    sh[t] = c;
    __syncthreads();
    for (int off = 1; off < 512; off <<= 1) {
        int v = (t >= off) ? sh[t - off] : 0;
        __syncthreads();
        sh[t] += v;
        __syncthreads();
    }
    if (t < NC_TOT) {
        int excl = sh[t] - c;
        int pre, gbase;
        if (t < CB1)      { pre = 0;           gbase = 0;  }
        else if (t < CB2) { pre = sh[CB1 - 1]; gbase = B1; }
        else if (t < CB3) { pre = sh[CB2 - 1]; gbase = B2; }
        else              { pre = sh[CB3 - 1]; gbase = B3; }
        int wb = excl - pre;
        gb[t] = wb;
        gcur[t] = gbase + wb;
    }
}

// binA: per-block chunk of 8192 edges -> LDS counting sort by coarse bin -> run-coalesced
// append into coarse-bin-contiguous staging. 512 threads (16 waves/CU at 73KB LDS) and a
// per-16-slot LUT replace the former per-element 9-deep binary search (latency killer).
__global__ __launch_bounds__(512) void binA(
        const int* __restrict__ d0, const int* __restrict__ s0, const float* __restrict__ v0,
        const int* __restrict__ d1, const int* __restrict__ s1, const float* __restrict__ v1,
        const int* __restrict__ d2, const int* __restrict__ s2, const float* __restrict__ v2,
        const int* __restrict__ d3, const int* __restrict__ s3, const float* __restrict__ v3,
        int* __restrict__ gcur, int2* __restrict__ stage) {
    __shared__ int2 buf[BATCH];          // 64 KB
    __shared__ int hist[NBIN];
    __shared__ int scx[NBIN];            // exclusive bases
    __shared__ int cur[NBIN];            // running scatter cursors
    __shared__ int obase[NBIN];          // global base reserved for this block's run per bin
    __shared__ short lut[BATCH / 16];    // bin of slot g*16
    int tid = threadIdx.x;
    int e0 = blockIdx.x * BATCH;
    int e1 = min(E_TOT, e0 + BATCH);

    hist[tid] = 0;
    __syncthreads();

    // pass 1: histogram (dst only)
    for (int i = e0 + tid; i < e1; i += 512) {
        int bin;
        if (i < B1)      bin = d0[i] >> CSH0;
        else if (i < B2) bin = CB1 + (d1[i - B1] >> CSH1);
        else if (i < B3) bin = CB2 + (d2[i - B2] >> CSH2);
        else             bin = CB3 + (d3[i - B3] >> CSH3);
        atomicAdd(&hist[bin], 1);
    }
    __syncthreads();

    // inclusive scan (512 threads, 1 elem each)
    int c = hist[tid];
    scx[tid] = c;
    __syncthreads();
    for (int off = 1; off < NBIN; off <<= 1) {
        int v = (tid >= off) ? scx[tid - off] : 0;
        __syncthreads();
        scx[tid] += v;
        __syncthreads();
    }
    int ex = scx[tid] - c;
    __syncthreads();
    scx[tid] = ex;
    cur[tid] = ex;
    if (c > 0) obase[tid] = atomicAdd(&gcur[tid], c);
    __syncthreads();

    // pass 2: re-read edges, scatter into LDS in bin order
    for (int i = e0 + tid; i < e1; i += 512) {
        int bin; int2 rec;
        if (i < B1) {
            int li = i;      int d = d0[li];
            rec.x = s0[li] | ((d & ((1 << CSH0) - 1)) << 17);
            rec.y = __float_as_int(v0[li]);
            bin = d >> CSH0;
        } else if (i < B2) {
            int li = i - B1; int d = d1[li];
            rec.x = s1[li] | ((d & ((1 << CSH1) - 1)) << 17);
            rec.y = __float_as_int(v1[li]);
            bin = CB1 + (d >> CSH1);
        } else if (i < B3) {
            int li = i - B2; int d = d2[li];
            rec.x = s2[li] | ((d & ((1 << CSH2) - 1)) << 17);
            rec.y = __float_as_int(v2[li]);
            bin = CB2 + (d >> CSH2);
        } else {
            int li = i - B3; int d = d3[li];
            rec.x = s3[li] | ((d & ((1 << CSH3) - 1)) << 17);
            rec.y = __float_as_int(v3[li]);
            bin = CB3 + (d >> CSH3);
        }
        int p = atomicAdd(&cur[bin], 1);
        buf[p] = rec;
    }
    // LUT: one binary search per 16-slot granule (parallel, once)
    {
        int slot = tid * 16;
        int lo = 0, hi = NBIN - 1;
        while (lo < hi) {
            int mid = (lo + hi + 1) >> 1;
            if (scx[mid] <= slot) lo = mid; else hi = mid - 1;
        }
        lut[tid] = (short)lo;
    }
    __syncthreads();

    // write out: start from lut granule, advance linearly (avg < 1 step)
    int cntE = e1 - e0;
    for (int j = tid; j < cntE; j += 512) {
        int lo = lut[j >> 4];
        while (lo + 1 < NBIN && scx[lo + 1] <= j) ++lo;
        stage[obase[lo] + (j - scx[lo])] = buf[j];
    }
}

__global__ __launch_bounds__(512) void binB(
        int* __restrict__ r0, int* __restrict__ r1,
        int* __restrict__ r2, int* __restrict__ r3,
        int2* __restrict__ e0, int2* __restrict__ e1,
        int2* __restrict__ e2, int2* __restrict__ e3,
        const int* __restrict__ gb, const int2* __restrict__ stage) {
    __shared__ int lc[1024];
    __shared__ int lcur[1024];
    int b = blockIdx.x;
    int* rp; int2* eo; int n, k, csh, ebase, Eg, nbEnd;
    if (b < CB1)       { k = b;       rp = r0; eo = e0; n = N_U; csh = CSH0; ebase = 0;  Eg = E_UB; nbEnd = CB1;    }
    else if (b < CB2)  { k = b - CB1; rp = r1; eo = e1; n = N_U; csh = CSH1; ebase = B1; Eg = E_UU; nbEnd = CB2;    }
    else if (b < CB3)  { k = b - CB2; rp = r2; eo = e2; n = N_B; csh = CSH2; ebase = B2; Eg = E_UB; nbEnd = CB3;    }
    else               { k = b - CB3; rp = r3; eo = e3; n = N_B; csh = CSH3; ebase = B3; Eg = E_BB; nbEnd = NC_TOT; }
    int lo = k << csh;
    int hi = min(n, lo + (1 << csh));
    int rows = hi - lo;
    int base = gb[b];
    int cnt = ((b + 1 < nbEnd) ? gb[b + 1] : Eg) - base;
    const int2* sp = stage + ebase + base;

    for (int j = threadIdx.x; j < 1024; j += 512) lc[j] = 0;
    __syncthreads();
    for (int i = threadIdx.x; i < cnt; i += 512)
        atomicAdd(&lc[((unsigned)sp[i].x) >> 17], 1);
    __syncthreads();
    for (int off = 1; off < 1024; off <<= 1) {
        int i0 = threadIdx.x, i1 = threadIdx.x + 512;
        int t0 = (i0 >= off) ? lc[i0 - off] : 0;
        int t1 = (i1 >= off) ? lc[i1 - off] : 0;
        __syncthreads();
        lc[i0] += t0;
        lc[i1] += t1;
        __syncthreads();
    }
    for (int j = threadIdx.x; j < rows; j += 512) {
        int exv = base + ((j > 0) ? lc[j - 1] : 0);
        rp[lo + j] = exv;
        lcur[j] = exv;
    }
    if (threadIdx.x == 0 && hi == n) rp[n] = Eg;
    __syncthreads();
    for (int i = threadIdx.x; i < cnt; i += 512) {
        int2 rec = sp[i];
        int p = atomicAdd(&lcur[((unsigned)rec.x) >> 17], 1);
        eo[p] = make_int2(rec.x & 0x1FFFF, rec.y);
    }
}

// ---------------- dense projection via MFMA (error-compensated bf16 split) ----------------

__global__ __launch_bounds__(256) void convW(const float* __restrict__ Wu, const float* __restrict__ Wb,
                                             short* __restrict__ Wuh, short* __restrict__ Wul,
                                             short* __restrict__ Wbh, short* __restrict__ Wbl) {
    int i = blockIdx.x * 256 + threadIdx.x;
    if (i >= 2 * IN_DIM * D) return;
    int m = i / (IN_DIM * D);
    int j = i - m * (IN_DIM * D);
    int k = j / D, col = j - k * D;          // W[k][col], row-major [384][128]
    float x = (m ? Wb : Wu)[j];
    unsigned hb = bf16rn(x);
    unsigned lb = bf16rn(x - __uint_as_float(hb << 16));
    int ct = col >> 4, lr = col & 15, ks = k >> 5, lg = (k >> 3) & 3, e = k & 7;
    int oi = ((ct * 12 + ks) * 64 + (lg * 16 + lr)) * 8 + e;
    (m ? Wbh : Wuh)[oi] = (short)hb;
    (m ? Wbl : Wul)[oi] = (short)lb;
}

__global__ __launch_bounds__(256) void gemm_mfma(
        const float* __restrict__ Xu, const float* __restrict__ Xb,
        const short* __restrict__ Wuh, const short* __restrict__ Wul,
        const short* __restrict__ Wbh, const short* __restrict__ Wbl,
        unsigned short* __restrict__ uch, float* __restrict__ usum,
        unsigned short* __restrict__ bch, float* __restrict__ bsum) {
    int l = threadIdx.x & 63, w = threadIdx.x >> 6;
    int wid = blockIdx.x * 4 + w;
    const float* X; const short *Wh, *Wl; unsigned short* ch; float* sm; int mBase;
    if (wid < NW_U) {
        X = Xu; Wh = Wuh; Wl = Wul; ch = uch; sm = usum; mBase = wid * 32;
    } else {
        int wb = wid - NW_U;
        if (wb >= NW_B) return;
        X = Xb; Wh = Wbh; Wl = Wbl; ch = bch; sm = bsum; mBase = wb * 32;
    }
    int lr = l & 15, lg = l >> 4;
    const float4* xr0 = (const float4*)(X + (size_t)(mBase + lr) * IN_DIM);
    const float4* xr1 = (const float4*)(X + (size_t)(mBase + 16 + lr) * IN_DIM);
    const short8v* bhp = (const short8v*)Wh + l;
    const short8v* blp = (const short8v*)Wl + l;

    f32x4 acc0[8], acc1[8];
#pragma unroll
    for (int ct = 0; ct < 8; ++ct) {
        acc0[ct] = (f32x4){0.f, 0.f, 0.f, 0.f};
        acc1[ct] = (f32x4){0.f, 0.f, 0.f, 0.f};
    }

#pragma unroll
    for (int ks = 0; ks < 12; ++ks) {
        float4 a0 = xr0[ks * 8 + lg * 2];
        float4 a1 = xr0[ks * 8 + lg * 2 + 1];
        float4 a2 = xr1[ks * 8 + lg * 2];
        float4 a3 = xr1[ks * 8 + lg * 2 + 1];
        short8v ah0, al0, ah1, al1;
        cvt8(a0, a1, ah0, al0);
        cvt8(a2, a3, ah1, al1);
#pragma unroll
        for (int ct = 0; ct < 8; ++ct) {
            short8v bh = bhp[(ct * 12 + ks) * 64];
            short8v bl = blp[(ct * 12 + ks) * 64];
            acc0[ct] = __builtin_amdgcn_mfma_f32_16x16x32_bf16(ah0, bh, acc0[ct], 0, 0, 0);
            acc1[ct] = __builtin_amdgcn_mfma_f32_16x16x32_bf16(ah1, bh, acc1[ct], 0, 0, 0);
            acc0[ct] = __builtin_amdgcn_mfma_f32_16x16x32_bf16(al0, bh, acc0[ct], 0, 0, 0);
            acc1[ct] = __builtin_amdgcn_mfma_f32_16x16x32_bf16(al1, bh, acc1[ct], 0, 0, 0);
            acc0[ct] = __builtin_amdgcn_mfma_f32_16x16x32_bf16(ah0, bl, acc0[ct], 0, 0, 0);
            acc1[ct] = __builtin_amdgcn_mfma_f32_16x16x32_bf16(ah1, bl, acc1[ct], 0, 0, 0);
        }
    }

    // C/D layout: col = lane&15, row = (lane>>4)*4 + reg  [HW-verified mapping]
#pragma unroll
    for (int ct = 0; ct < 8; ++ct) {
        int col = ct * 16 + lr;
#pragma unroll
        for (int r = 0; r < 4; ++r) {
            int row0 = mBase + lg * 4 + r;
            int row1 = mBase + 16 + lg * 4 + r;
            size_t o0 = (size_t)row0 * D + col;
            size_t o1 = (size_t)row1 * D + col;
            float v0 = acc0[ct][r], v1 = acc1[ct][r];
            sm[o0] = v0; ch[o0] = (unsigned short)bf16rn(v0);
            sm[o1] = v1; ch[o1] = (unsigned short)bf16rn(v1);
        }
    }
}

// ---------------- fused pull SpMM (user + biz in one dispatch per layer) ----------------

__global__ void spmm_fused(const int* __restrict__ rp_bu, const int2* __restrict__ e_bu,
                           const int* __restrict__ rp_uu, const int2* __restrict__ e_uu,
                           const int* __restrict__ rp_ub, const int2* __restrict__ e_ub,
                           const int* __restrict__ rp_bb, const int2* __restrict__ e_bb,
                           const uint4* __restrict__ ucur, const uint4* __restrict__ bcur,
                           uint4* __restrict__ unxt, uint4* __restrict__ bnxt,
                           float4* __restrict__ usum, float4* __restrict__ bsum) {
    int wave = threadIdx.x >> 6;
    int lane = threadIdx.x & 63;
    int q = lane >> 4;
    int l = lane & 15;
    int idx = blockIdx.x * 4 + wave;
    const int *rp1, *rp2; const int2 *ee1, *ee2; const uint4 *x1, *x2;
    uint4* y; float4* sm; int r;
    if (idx < N_U) {
        r = idx;
        rp1 = rp_bu; ee1 = e_bu; rp2 = rp_uu; ee2 = e_uu;
        x1 = bcur; x2 = ucur; y = unxt; sm = usum;
    } else {
        r = idx - N_U;
        if (r >= N_B) return;
        rp1 = rp_ub; ee1 = e_ub; rp2 = rp_bb; ee2 = e_bb;
        x1 = ucur; x2 = bcur; y = bnxt; sm = bsum;
    }

    float acc[8];
#pragma unroll
    for (int k = 0; k < 8; ++k) acc[k] = 0.f;

#pragma unroll
    for (int pass = 0; pass < 2; ++pass) {
        const int* rp = pass ? rp2 : rp1;
        const int2* edges = pass ? ee2 : ee1;
        const uint4* xv = pass ? x2 : x1;
        int s = rp[r], e = rp[r + 1];
        int i = s;
        for (; i + 8 <= e; i += 8) {
            int2 edA = edges[i + q];
            int2 edB = edges[i + 4 + q];
            uint4 uA = xv[(size_t)edA.x * 16 + l];
            uint4 uB = xv[(size_t)edB.x * 16 + l];
            fma8(acc, __int_as_float(edA.y), uA);
            fma8(acc, __int_as_float(edB.y), uB);
        }
        if (i < e) {
            int idx2 = i + q;
            bool valid = idx2 < e;
            int2 ed = edges[valid ? idx2 : (e - 1)];
            uint4 u = xv[(size_t)ed.x * 16 + l];
            fma8(acc, valid ? __int_as_float(ed.y) : 0.f, u);
            i += 4;
            if (i < e) {
                idx2 = i + q;
                valid = idx2 < e;
                int2 ed2 = edges[valid ? idx2 : (e - 1)];
                uint4 u2 = xv[(size_t)ed2.x * 16 + l];
                fma8(acc, valid ? __int_as_float(ed2.y) : 0.f, u2);
            }
        }
    }

#pragma unroll
    for (int k = 0; k < 8; ++k) {
        acc[k] += __shfl_xor(acc[k], 16);
        acc[k] += __shfl_xor(acc[k], 32);
    }

    if (q == 0) {
        uint4 p;
        p.x = bf16rn(acc[0]) | (bf16rn(acc[1]) << 16);
        p.y = bf16rn(acc[2]) | (bf16rn(acc[3]) << 16);
        p.z = bf16rn(acc[4]) | (bf16rn(acc[5]) << 16);
        p.w = bf16rn(acc[6]) | (bf16rn(acc[7]) << 16);
        y[(size_t)r * 16 + l] = p;
        float4* sp = sm + (size_t)r * 32 + 2 * l;
        float4 s0 = sp[0], s1 = sp[1];
        s0.x += acc[0]; s0.y += acc[1]; s0.z += acc[2]; s0.w += acc[3];
        s1.x += acc[4]; s1.y += acc[5]; s1.z += acc[6]; s1.w += acc[7];
        sp[0] = s0; sp[1] = s1;
    }
}

// ---------------- normalize (u_sum and b_sum are contiguous in out) ----------------

__global__ void norm_kernel(float* __restrict__ out, int n) {
    int wave = threadIdx.x >> 6;
    int lane = threadIdx.x & 63;
    int r = blockIdx.x * 4 + wave;
    if (r >= n) return;
    float2* p = (float2*)out + (size_t)r * 64 + lane;
    float2 v = *p;
    v.x *= 0.25f;
    v.y *= 0.25f;
    float ss = v.x * v.x + v.y * v.y;
    for (int off = 32; off > 0; off >>= 1) ss += __shfl_down(ss, off);
    ss = __shfl(ss, 0);
    float inv = 1.f / fmaxf(sqrtf(ss), 1e-12f);
    v.x *= inv;
    v.y *= inv;
    *p = v;
}

// ---------------- launch ----------------

extern "C" void kernel_launch(void* const* d_in, const int* in_sizes, int n_in,
                              void* d_out, int out_size, void* d_ws, size_t ws_size,
                              hipStream_t stream) {
    const float* user_feat = (const float*)d_in[0];
    const float* biz_feat  = (const float*)d_in[1];
    const float* W_user    = (const float*)d_in[2];
    const float* W_biz     = (const float*)d_in[3];
    const int*   ub_u      = (const int*)d_in[4];
    const int*   ub_b      = (const int*)d_in[5];
    const float* val_ub    = (const float*)d_in[6];
    const float* val_bu    = (const float*)d_in[7];
    const int*   uu_src    = (const int*)d_in[8];
    const int*   uu_dst    = (const int*)d_in[9];
    const float* uu_val    = (const float*)d_in[10];
    const int*   bb_src    = (const int*)d_in[11];
    const int*   bb_dst    = (const int*)d_in[12];
    const float* bb_val    = (const float*)d_in[13];

    float* out   = (float*)d_out;
    float* u_sum = out;
    float* b_sum = out + (size_t)N_U * D;

    char* ws = (char*)d_ws;
    size_t off = 0;
    auto alloc = [&](size_t bytes) -> void* {
        void* p = ws + off;
        off += (bytes + 255) & ~(size_t)255;
        return p;
    };
    unsigned* u_curh = (unsigned*)alloc((size_t)N_U * 64 * 4);   // bf16 [N_U,128]
    unsigned* b_curh = (unsigned*)alloc((size_t)N_B * 64 * 4);
    int2* e_bu = (int2*)alloc((size_t)E_UB * 8);
    int2* e_uu = (int2*)alloc((size_t)E_UU * 8);
    int2* e_ub = (int2*)alloc((size_t)E_UB * 8);
    int2* e_bb = (int2*)alloc((size_t)E_BB * 8);
    int*  ccnt = (int*)alloc(NC_TOT * 4);
    int*  gb   = (int*)alloc(NC_TOT * 4);
    int*  gcur = (int*)alloc(NC_TOT * 4);
    int*  rp_bu = (int*)alloc((N_U + 1) * 4);
    int*  rp_uu = (int*)alloc((N_U + 1) * 4);
    int*  rp_ub = (int*)alloc((N_B + 1) * 4);
    int*  rp_bb = (int*)alloc((N_B + 1) * 4);
    short* Wuh = (short*)alloc((size_t)D * IN_DIM * 2);
    short* Wul = (short*)alloc((size_t)D * IN_DIM * 2);
    short* Wbh = (short*)alloc((size_t)D * IN_DIM * 2);
    short* Wbl = (short*)alloc((size_t)D * IN_DIM * 2);
    // staging region; u_nxth/b_nxth alias its head (used only after binB completes)
    int2* stage = (int2*)alloc((size_t)E_TOT * 8);
    unsigned* u_nxth = (unsigned*)stage;
    unsigned* b_nxth = (unsigned*)((char*)stage + (size_t)N_U * 64 * 4);

    hipMemsetAsync(ccnt, 0, sizeof(int) * NC_TOT, stream);

    coarse_count<<<1024, 256, 0, stream>>>(ub_u, uu_dst, ub_b, bb_dst, ccnt);
    cscan<<<1, 512, 0, stream>>>(ccnt, gb, gcur);
    binA<<<NCHUNK, 512, 0, stream>>>(ub_u,   ub_b,   val_bu,
                                     uu_dst, uu_src, uu_val,
                                     ub_b,   ub_u,   val_ub,
                                     bb_dst, bb_src, bb_val,
                                     gcur, stage);
    binB<<<NC_TOT, 512, 0, stream>>>(rp_bu, rp_uu, rp_ub, rp_bb,
                                     e_bu, e_uu, e_ub, e_bb, gb, stage);

    convW<<<(2 * IN_DIM * D + 255) / 256, 256, 0, stream>>>(W_user, W_biz, Wuh, Wul, Wbh, Wbl);
    gemm_mfma<<<(NW_U + NW_B + 3) / 4, 256, 0, stream>>>(
        user_feat, biz_feat, Wuh, Wul, Wbh, Wbl,
        (unsigned short*)u_curh, u_sum, (unsigned short*)b_curh, b_sum);

    for (int l = 0; l < 3; ++l) {
        spmm_fused<<<(N_U + N_B) / 4, 256, 0, stream>>>(
            rp_bu, e_bu, rp_uu, e_uu, rp_ub, e_ub, rp_bb, e_bb,
            (const uint4*)u_curh, (const uint4*)b_curh,
            (uint4*)u_nxth, (uint4*)b_nxth, (float4*)u_sum, (float4*)b_sum);
        unsigned* t;
        t = u_curh; u_curh = u_nxth; u_nxth = t;
        t = b_curh; b_curh = b_nxth; b_nxth = t;
    }

    norm_kernel<<<(N_U + N_B) / 4, 256, 0, stream>>>(out, N_U + N_B);
}